// Round 3
// baseline (3858.014 us; speedup 1.0000x reference)
//
#include <hip/hip_runtime.h>
#include <hip/hip_bf16.h>

typedef __hip_bfloat16 bf16;
typedef unsigned int uint32;

#define N_ITEMS_C 50000
#define N_USERS_C 20000
#define N_NODES_C 70000
#define NNZ_C 800000
#define NSESS 1024
#define LP 49
#define NTOK (NSESS * LP)   // 50176

__device__ __forceinline__ float bflo(uint32 u) { return __uint_as_float(u << 16); }
__device__ __forceinline__ float bfhi(uint32 u) { return __uint_as_float(u & 0xffff0000u); }
__device__ __forceinline__ uint32 packbf(float a, float b) {
    return (uint32)__bfloat16_as_ushort(__float2bfloat16(a)) |
           ((uint32)__bfloat16_as_ushort(__float2bfloat16(b)) << 16);
}

// ---------------- init: ha = concat(id_emb, user_emb) f32 copy ----------------
__global__ void init_ha_kernel(const float4* __restrict__ idq, const float4* __restrict__ usq,
                               float4* __restrict__ ha4) {
    int i = blockIdx.x * 256 + threadIdx.x;           // float4 index, 2,240,000 total
    ha4[i] = (i < 1600000) ? idq[i] : usq[i - 1600000];
}

// ---------------- generic GEMM: out[M,128] = op((A(+A2))[M,128] @ W[128,128]^T + bias) ----
// A rows optionally indirected through rowmap. W row-major (n,k) f32, staged as bf16.
// LDS: As 33.3KB + Ws 16.9KB = 50.2KB (<64KB/WG, 3 blocks/CU on 160KB LDS)
__global__ __launch_bounds__(256, 3) void gemm128_kernel(
    const float* __restrict__ A, const float* __restrict__ A2,
    const int* __restrict__ rowmap,
    const float* __restrict__ W, const float* __restrict__ bias,
    float* __restrict__ out, int M, int relu)
{
    __shared__ float As[128][65];               // [k][m]
    __shared__ __align__(8) bf16 Ws[128][66];   // [n][k-half], bf16 pairs, odd dword stride
    const int tid = threadIdx.x;
    const int row0 = blockIdx.x * 64;
#pragma unroll
    for (int i = 0; i < 8; ++i) {               // stage A (64 rows x 128 k), f32
        int id = i * 256 + tid;
        int r = id >> 5;
        int c4 = (id & 31) << 2;
        float4 v = make_float4(0.f, 0.f, 0.f, 0.f);
        int gr = row0 + r;
        if (gr < M) {
            int ar = rowmap ? rowmap[gr] : gr;
            v = *(const float4*)&A[(size_t)ar * 128 + c4];
            if (A2) {
                float4 w = *(const float4*)&A2[(size_t)ar * 128 + c4];
                v.x += w.x; v.y += w.y; v.z += w.z; v.w += w.w;
            }
        }
        As[c4 + 0][r] = v.x; As[c4 + 1][r] = v.y; As[c4 + 2][r] = v.z; As[c4 + 3][r] = v.w;
    }
    const int m0 = (tid & 15) * 4;
    const int n0 = (tid >> 4) * 8;
    float acc[4][8];
#pragma unroll
    for (int i = 0; i < 4; ++i)
#pragma unroll
        for (int j = 0; j < 8; ++j) acc[i][j] = 0.f;

    for (int p = 0; p < 2; ++p) {               // two K-halves of W
        if (p) __syncthreads();                 // previous-phase reads done
#pragma unroll
        for (int i = 0; i < 8; ++i) {           // stage W[:, p*64 .. p*64+64) as bf16
            int id = i * 256 + tid;             // 2048 float4
            int n = id >> 4, koff = (id & 15) * 4;
            float4 w = *(const float4*)&W[(size_t)n * 128 + p * 64 + koff];
            *(uint32*)&Ws[n][koff]     = packbf(w.x, w.y);
            *(uint32*)&Ws[n][koff + 2] = packbf(w.z, w.w);
        }
        __syncthreads();
        for (int k2 = 0; k2 < 32; ++k2) {
            int kk = p * 64 + 2 * k2;
            float av0[4], av1[4];
#pragma unroll
            for (int i = 0; i < 4; ++i) { av0[i] = As[kk][m0 + i]; av1[i] = As[kk + 1][m0 + i]; }
#pragma unroll
            for (int j = 0; j < 8; ++j) {
                uint32 wp = *(const uint32*)&Ws[n0 + j][2 * k2];
                float w0 = bflo(wp), w1 = bfhi(wp);
#pragma unroll
                for (int i = 0; i < 4; ++i)
                    acc[i][j] = fmaf(av1[i], w1, fmaf(av0[i], w0, acc[i][j]));
            }
        }
    }
    float bv[8];
#pragma unroll
    for (int j = 0; j < 8; ++j) bv[j] = bias ? bias[n0 + j] : 0.f;
#pragma unroll
    for (int i = 0; i < 4; ++i) {
        int r = row0 + m0 + i;
        if (r < M) {
            float vv[8];
#pragma unroll
            for (int j = 0; j < 8; ++j) {
                float v = acc[i][j] + bv[j];
                vv[j] = relu ? fmaxf(v, 0.f) : v;
            }
            *(float4*)&out[(size_t)r * 128 + n0] = make_float4(vv[0], vv[1], vv[2], vv[3]);
            *(float4*)&out[(size_t)r * 128 + n0 + 4] = make_float4(vv[4], vv[5], vv[6], vv[7]);
        }
    }
}

// ---------------- edge scatter: msg[rows[e]] += wh[cols[e]] * val[e] ----------------
__global__ __launch_bounds__(256) void scatter_kernel(
    const float* __restrict__ wh, float* __restrict__ msg,
    const int* __restrict__ rows, const int* __restrict__ cols,
    const float* __restrict__ vals)
{
    int e = blockIdx.x * 2 + (threadIdx.x >> 7);
    int d = threadIdx.x & 127;
    int row = rows[e];
    int col = cols[e];
    float v = vals[e];
    unsafeAtomicAdd(&msg[(size_t)row * 128 + d], wh[(size_t)col * 128 + d] * v);
}

// ---------------- session prep: lens, ht rowmap, target & u_type outputs (f32) ----------
__global__ void session_prep_kernel(const int* __restrict__ ids, const int* __restrict__ uid,
                                    const float* __restrict__ u_type,
                                    int* __restrict__ lens, int* __restrict__ rowmap,
                                    float* __restrict__ out_target, float* __restrict__ out_utype)
{
    int n = blockIdx.x * 256 + threadIdx.x;
    if (n >= NSESS) return;
    int b = n & 255, s = n >> 8;
    const int* row = ids + (size_t)(b * 4 + s) * 50;
    int len = 0;
#pragma unroll
    for (int l = 0; l < 50; ++l) len += (row[l] != 0) ? 1 : 0;
    lens[n] = len;
    rowmap[n] = n * LP + (len - 2);
    out_target[n] = (float)row[len - 1];
    out_utype[n] = u_type[b];
}

// ---------------- c_hist gather (must run before ha is reused) ----------------
__global__ void chist_kernel(const float* __restrict__ ha, const int* __restrict__ uid,
                             float* __restrict__ chist) {
    int n = blockIdx.x, d = threadIdx.x;
    chist[(size_t)n * 128 + d] = ha[(size_t)(N_ITEMS_C + uid[n & 255]) * 128 + d];
}

// ---------------- token embedding gather ----------------
__global__ void h0_gather_kernel(const float* __restrict__ id_emb, const int* __restrict__ ids,
                                 const int* __restrict__ lens, float* __restrict__ h0) {
    int g = blockIdx.x, d = threadIdx.x;
    int n = g / LP;
    int tt = g - n * LP;
    int len = lens[n];
    int b = n & 255, s = n >> 8;
    int id = (tt < len - 1) ? ids[(size_t)(b * 4 + s) * 50 + tt] : 0;
    h0[(size_t)g * 128 + d] = id_emb[(size_t)id * 128 + d];
}

// ---------------- fused GRU cell over all tokens (in-place on h) ----------------
// LDS: m_s 16KB + h_s 8KB + w_s 33.3KB = 57.9KB (<64KB/WG)
__global__ __launch_bounds__(256, 2) void gru_kernel(
    const float* __restrict__ hEi, const float* __restrict__ hEo,
    float* __restrict__ h, const int* __restrict__ lens,
    const float* __restrict__ w_ih, const float* __restrict__ w_hh,
    const float* __restrict__ b_ih, const float* __restrict__ b_hh,
    const float* __restrict__ b_iah, const float* __restrict__ b_oah)
{
    __shared__ float m_s[16][256];
    __shared__ float h_s[16][128];
    __shared__ __align__(8) bf16 w_s[128][130];   // one 128x128 bf16 tile, odd dword stride
    const int tid = threadIdx.x;
    const int g0 = blockIdx.x * 16;

    for (int i = 0; i < 16; ++i) {
        int id = i * 256 + tid;
        int t = id >> 8, k = id & 255;
        int g = g0 + t;
        int n = g / LP;
        int tt = g - n * LP;
        int len = lens[n];
        float v;
        if (k < 128) {
            v = b_iah[k];
            if (tt >= 1 && tt < len - 1) v += hEi[(size_t)(g - 1) * 128 + k];
        } else {
            int kk = k - 128;
            v = b_oah[kk];
            if (tt < len - 2) v += hEo[(size_t)(g + 1) * 128 + kk];
        }
        m_s[t][k] = v;
    }
    for (int i = 0; i < 8; ++i) {
        int id = i * 256 + tid;
        int t = id >> 7, k = id & 127;
        h_s[t][k] = h[(size_t)(g0 + t) * 128 + k];
    }

    const int jj = tid & 127;
    const int tg = (tid >> 7) * 8;
    float gi_g[3][8], gh_g[3][8];

    for (int c = 0; c < 3; ++c) {
        float ai[8] = {0, 0, 0, 0, 0, 0, 0, 0};
        // --- two K-halves of w_ih chunk c ---
        for (int p = 0; p < 2; ++p) {
            __syncthreads();    // staging-data ready fence from prior phase / initial stage
            {
                const float2* wg = (const float2*)(w_ih + (size_t)c * 32768);
                for (int i = 0; i < 32; ++i) {
                    int d2 = i * 256 + tid;              // 8192 pairs: 128 rows x 64 pairs
                    int jr = d2 >> 6, pi = d2 & 63;
                    float2 w = wg[(size_t)jr * 128 + p * 64 + pi];
                    *(uint32*)&w_s[jr][pi * 2] = packbf(w.x, w.y);
                }
            }
            __syncthreads();
            for (int k2 = 0; k2 < 64; ++k2) {
                uint32 wp = *(const uint32*)&w_s[jj][k2 * 2];
                float w0 = bflo(wp), w1 = bfhi(wp);
#pragma unroll
                for (int u = 0; u < 8; ++u) {
                    float2 m2 = *(const float2*)&m_s[tg + u][p * 128 + k2 * 2];
                    ai[u] += m2.x * w0 + m2.y * w1;
                }
            }
        }
        // --- w_hh chunk c ---
        __syncthreads();
        {
            const float2* wg2 = (const float2*)(w_hh + (size_t)c * 16384);
            for (int i = 0; i < 32; ++i) {
                int d2 = i * 256 + tid;                  // 8192 pairs: 128 rows x 64 pairs
                int jr = d2 >> 6, pi = d2 & 63;
                float2 w = wg2[(size_t)jr * 64 + pi];
                *(uint32*)&w_s[jr][pi * 2] = packbf(w.x, w.y);
            }
        }
        __syncthreads();
        float ah[8] = {0, 0, 0, 0, 0, 0, 0, 0};
        for (int k2 = 0; k2 < 64; ++k2) {
            uint32 wp = *(const uint32*)&w_s[jj][k2 * 2];
            float w0 = bflo(wp), w1 = bfhi(wp);
#pragma unroll
            for (int u = 0; u < 8; ++u) {
                float2 h2 = *(const float2*)&h_s[tg + u][k2 * 2];
                ah[u] += h2.x * w0 + h2.y * w1;
            }
        }
        float bi = b_ih[c * 128 + jj];
        float bh = b_hh[c * 128 + jj];
#pragma unroll
        for (int u = 0; u < 8; ++u) {
            gi_g[c][u] = ai[u] + bi;
            gh_g[c][u] = ah[u] + bh;
        }
    }
#pragma unroll
    for (int u = 0; u < 8; ++u) {
        int t = tg + u;
        float ho = h_s[t][jj];
        float rg = 1.f / (1.f + expf(-(gi_g[0][u] + gh_g[0][u])));
        float zg = 1.f / (1.f + expf(-(gi_g[1][u] + gh_g[1][u])));
        float ng = tanhf(gi_g[2][u] + rg * gh_g[2][u]);
        h[(size_t)(g0 + t) * 128 + jj] = ng + zg * (ho - ng);
    }
}

// ---------------- attention readout + fuse layer -> reps (f32 out) ----------------
__global__ __launch_bounds__(128) void attn_fuse_kernel(
    const float* __restrict__ q1h, const float* __restrict__ q2h,
    const float* __restrict__ h, const float* __restrict__ chist,
    const int* __restrict__ lens, const float* __restrict__ att_w,
    const float* __restrict__ fuse_w, const float* __restrict__ fuse_b,
    float* __restrict__ out)
{
    __shared__ float q1s[128], aws[128], al[64], cv[256];
    const int n = blockIdx.x, tid = threadIdx.x;
    q1s[tid] = q1h[(size_t)n * 128 + tid];
    aws[tid] = att_w[tid];
    if (tid < 64) al[tid] = 0.f;
    __syncthreads();
    const int len = lens[n];
    if (tid < len - 1) {
        const float* q2 = &q2h[(size_t)(n * LP + tid) * 128];
        float s = 0.f;
        for (int d = 0; d < 128; ++d) {
            float x = q1s[d] + q2[d];
            s += aws[d] / (1.f + expf(-x));
        }
        al[tid] = s;
    }
    __syncthreads();
    float ssum = 0.f;
    for (int t = 0; t < len - 1; ++t) ssum += al[t];
    float inv = 1.f / (ssum + 1e-8f);
    float c = 0.f;
    for (int t = 0; t < len - 1; ++t)
        c += al[t] * inv * h[(size_t)(n * LP + t) * 128 + tid];
    cv[tid] = c;
    cv[128 + tid] = chist[(size_t)n * 128 + tid];
    __syncthreads();
    float s = fuse_b[tid];
    const float* fr = fuse_w + (size_t)tid * 256;
    for (int k = 0; k < 256; ++k) s += cv[k] * fr[k];
    out[(size_t)n * 128 + tid] = s;
}

// ============================================================================
extern "C" void kernel_launch(void* const* d_in, const int* in_sizes, int n_in,
                              void* d_out, int out_size, void* d_ws, size_t ws_size,
                              hipStream_t stream)
{
    const float* id_emb   = (const float*)d_in[0];
    const float* user_emb = (const float*)d_in[1];
    const float* lin_r_w  = (const float*)d_in[2];
    const float* upi_w    = (const float*)d_in[3];
    const float* upi_b    = (const float*)d_in[4];
    const float* upu_w    = (const float*)d_in[5];
    const float* upu_b    = (const float*)d_in[6];
    const float* w_ih     = (const float*)d_in[7];
    const float* w_hh     = (const float*)d_in[8];
    const float* b_ih     = (const float*)d_in[9];
    const float* b_hh     = (const float*)d_in[10];
    const float* b_iah    = (const float*)d_in[11];
    const float* b_oah    = (const float*)d_in[12];
    const float* ei_w     = (const float*)d_in[13];
    const float* ei_b     = (const float*)d_in[14];
    const float* eo_w     = (const float*)d_in[15];
    const float* eo_b     = (const float*)d_in[16];
    const float* q1_w     = (const float*)d_in[17];
    const float* q2_w     = (const float*)d_in[18];
    const float* att_w    = (const float*)d_in[19];
    const float* fuse_w   = (const float*)d_in[20];
    const float* fuse_b   = (const float*)d_in[21];
    const int*  rel_rows  = (const int*)d_in[22];
    const int*  rel_cols  = (const int*)d_in[23];
    const float* rel_vals = (const float*)d_in[24];
    const int*  ids       = (const int*)d_in[25];
    const int*  uid       = (const int*)d_in[26];
    const float* u_type   = (const float*)d_in[27];
    float* out = (float*)d_out;   // f32 outputs: reps[131072] | target[1024] | u_type[1024]

    float* ha    = (float*)d_ws;          // 8,960,000 f  (node features, f32)
    float* bufA  = ha   + 8960000;        // 8,960,000 f  (Wh, then h tokens)
    float* bufB  = bufA + 8960000;        // 8,960,000 f  (msg, then hEi, then q2h)
    float* q1h   = bufB + 8960000;        // 131,072 f
    float* chist = q1h  + 131072;         // 131,072 f
    int*   lens  = (int*)(chist + 131072);// 1024
    int*   rowmap= lens + 1024;           // 1024
    if (ws_size < (size_t)27144192 * 4 + 4096) return;  // ~108.6 MB needed

    // ---- global HGNN ----
    init_ha_kernel<<<8750, 256, 0, stream>>>((const float4*)id_emb, (const float4*)user_emb,
                                             (float4*)ha);
    for (int k = 0; k < 2; ++k) {
        hipMemsetAsync(bufB, 0, (size_t)8960000 * 4, stream);
        for (int r = 0; r < 3; ++r) {
            gemm128_kernel<<<1094, 256, 0, stream>>>(ha, nullptr, nullptr,
                lin_r_w + (size_t)(k * 3 + r) * 16384, nullptr, bufA, N_NODES_C, 0);
            scatter_kernel<<<NNZ_C / 2, 256, 0, stream>>>(bufA, bufB,
                rel_rows + (size_t)r * NNZ_C, rel_cols + (size_t)r * NNZ_C,
                rel_vals + (size_t)r * NNZ_C);
        }
        gemm128_kernel<<<782, 256, 0, stream>>>(bufB, ha, nullptr,
            upi_w + (size_t)k * 16384, upi_b + k * 128, ha, N_ITEMS_C, 1);
        gemm128_kernel<<<313, 256, 0, stream>>>(bufB + (size_t)N_ITEMS_C * 128,
            ha + (size_t)N_ITEMS_C * 128, nullptr,
            upu_w + (size_t)k * 16384, upu_b + k * 128, ha + (size_t)N_ITEMS_C * 128, N_USERS_C, 1);
    }

    // ---- session branch ----
    session_prep_kernel<<<4, 256, 0, stream>>>(ids, uid, u_type, lens, rowmap,
        out + 131072, out + 132096);
    chist_kernel<<<NSESS, 128, 0, stream>>>(ha, uid, chist);     // before ha is reused!
    h0_gather_kernel<<<NTOK, 128, 0, stream>>>(id_emb, ids, lens, bufA);
    gemm128_kernel<<<784, 256, 0, stream>>>(bufA, nullptr, nullptr, ei_w, ei_b, bufB, NTOK, 0);
    gemm128_kernel<<<784, 256, 0, stream>>>(bufA, nullptr, nullptr, eo_w, eo_b, ha, NTOK, 0);
    gru_kernel<<<NTOK / 16, 256, 0, stream>>>(bufB, ha, bufA, lens,
        w_ih, w_hh, b_ih, b_hh, b_iah, b_oah);
    gemm128_kernel<<<784, 256, 0, stream>>>(bufA, nullptr, nullptr, q2_w, nullptr, bufB, NTOK, 0);
    gemm128_kernel<<<16, 256, 0, stream>>>(bufA, nullptr, rowmap, q1_w, nullptr, q1h, NSESS, 0);
    attn_fuse_kernel<<<NSESS, 128, 0, stream>>>(q1h, bufB, bufA, chist, lens,
        att_w, fuse_w, fuse_b, out);
}

// Round 4
// 3364.757 us; speedup vs baseline: 1.1466x; 1.1466x over previous
//
#include <hip/hip_runtime.h>
#include <hip/hip_bf16.h>

typedef __hip_bfloat16 bf16;
typedef unsigned int uint32;

#define N_ITEMS_C 50000
#define N_USERS_C 20000
#define N_NODES_C 70000
#define NNZ_C 800000
#define NSESS 1024
#define LP 49
#define NTOK (NSESS * LP)   // 50176

__device__ __forceinline__ float bflo(uint32 u) { return __uint_as_float(u << 16); }
__device__ __forceinline__ float bfhi(uint32 u) { return __uint_as_float(u & 0xffff0000u); }
__device__ __forceinline__ uint32 packbf(float a, float b) {
    return (uint32)__bfloat16_as_ushort(__float2bfloat16(a)) |
           ((uint32)__bfloat16_as_ushort(__float2bfloat16(b)) << 16);
}

// ---------------- init: ha = concat(id_emb, user_emb) f32 copy ----------------
__global__ void init_ha_kernel(const float4* __restrict__ idq, const float4* __restrict__ usq,
                               float4* __restrict__ ha4) {
    int i = blockIdx.x * 256 + threadIdx.x;           // float4 index, 2,240,000 total
    ha4[i] = (i < 1600000) ? idq[i] : usq[i - 1600000];
}

// ---------------- generic GEMM: out[M,128] = op((A(+A2))[M,128] @ W[128,128]^T + bias) ----
// A rows optionally indirected through rowmap. W row-major (n,k) f32, staged as bf16.
// LDS: As 33.3KB + Ws 16.9KB = 50.2KB (<64KB/WG, 3 blocks/CU on 160KB LDS)
__global__ __launch_bounds__(256, 3) void gemm128_kernel(
    const float* __restrict__ A, const float* __restrict__ A2,
    const int* __restrict__ rowmap,
    const float* __restrict__ W, const float* __restrict__ bias,
    float* __restrict__ out, int M, int relu)
{
    __shared__ float As[128][65];               // [k][m]
    __shared__ __align__(8) bf16 Ws[128][66];   // [n][k-half], bf16 pairs, odd dword stride
    const int tid = threadIdx.x;
    const int row0 = blockIdx.x * 64;
#pragma unroll
    for (int i = 0; i < 8; ++i) {               // stage A (64 rows x 128 k), f32
        int id = i * 256 + tid;
        int r = id >> 5;
        int c4 = (id & 31) << 2;
        float4 v = make_float4(0.f, 0.f, 0.f, 0.f);
        int gr = row0 + r;
        if (gr < M) {
            int ar = rowmap ? rowmap[gr] : gr;
            v = *(const float4*)&A[(size_t)ar * 128 + c4];
            if (A2) {
                float4 w = *(const float4*)&A2[(size_t)ar * 128 + c4];
                v.x += w.x; v.y += w.y; v.z += w.z; v.w += w.w;
            }
        }
        As[c4 + 0][r] = v.x; As[c4 + 1][r] = v.y; As[c4 + 2][r] = v.z; As[c4 + 3][r] = v.w;
    }
    const int m0 = (tid & 15) * 4;
    const int n0 = (tid >> 4) * 8;
    float acc[4][8];
#pragma unroll
    for (int i = 0; i < 4; ++i)
#pragma unroll
        for (int j = 0; j < 8; ++j) acc[i][j] = 0.f;

    for (int p = 0; p < 2; ++p) {               // two K-halves of W
        if (p) __syncthreads();                 // previous-phase reads done
#pragma unroll
        for (int i = 0; i < 8; ++i) {           // stage W[:, p*64 .. p*64+64) as bf16
            int id = i * 256 + tid;             // 2048 float4
            int n = id >> 4, koff = (id & 15) * 4;
            float4 w = *(const float4*)&W[(size_t)n * 128 + p * 64 + koff];
            *(uint32*)&Ws[n][koff]     = packbf(w.x, w.y);
            *(uint32*)&Ws[n][koff + 2] = packbf(w.z, w.w);
        }
        __syncthreads();
        for (int k2 = 0; k2 < 32; ++k2) {
            int kk = p * 64 + 2 * k2;
            float av0[4], av1[4];
#pragma unroll
            for (int i = 0; i < 4; ++i) { av0[i] = As[kk][m0 + i]; av1[i] = As[kk + 1][m0 + i]; }
#pragma unroll
            for (int j = 0; j < 8; ++j) {
                uint32 wp = *(const uint32*)&Ws[n0 + j][2 * k2];
                float w0 = bflo(wp), w1 = bfhi(wp);
#pragma unroll
                for (int i = 0; i < 4; ++i)
                    acc[i][j] = fmaf(av1[i], w1, fmaf(av0[i], w0, acc[i][j]));
            }
        }
    }
    float bv[8];
#pragma unroll
    for (int j = 0; j < 8; ++j) bv[j] = bias ? bias[n0 + j] : 0.f;
#pragma unroll
    for (int i = 0; i < 4; ++i) {
        int r = row0 + m0 + i;
        if (r < M) {
            float vv[8];
#pragma unroll
            for (int j = 0; j < 8; ++j) {
                float v = acc[i][j] + bv[j];
                vv[j] = relu ? fmaxf(v, 0.f) : v;
            }
            *(float4*)&out[(size_t)r * 128 + n0] = make_float4(vv[0], vv[1], vv[2], vv[3]);
            *(float4*)&out[(size_t)r * 128 + n0 + 4] = make_float4(vv[4], vv[5], vv[6], vv[7]);
        }
    }
}

// ---------------- edge scatter: msg[rows[e]] += wh[cols[e]] * val[e] ----------------
__global__ __launch_bounds__(256) void scatter_kernel(
    const float* __restrict__ wh, float* __restrict__ msg,
    const int* __restrict__ rows, const int* __restrict__ cols,
    const float* __restrict__ vals)
{
    int e = blockIdx.x * 2 + (threadIdx.x >> 7);
    int d = threadIdx.x & 127;
    int row = rows[e];
    int col = cols[e];
    float v = vals[e];
    unsafeAtomicAdd(&msg[(size_t)row * 128 + d], wh[(size_t)col * 128 + d] * v);
}

// ---------------- session prep: lens, ht rowmap, target & u_type outputs (f32) ----------
__global__ void session_prep_kernel(const int* __restrict__ ids, const int* __restrict__ uid,
                                    const float* __restrict__ u_type,
                                    int* __restrict__ lens, int* __restrict__ rowmap,
                                    float* __restrict__ out_target, float* __restrict__ out_utype)
{
    int n = blockIdx.x * 256 + threadIdx.x;
    if (n >= NSESS) return;
    int b = n & 255, s = n >> 8;
    const int* row = ids + (size_t)(b * 4 + s) * 50;
    int len = 0;
#pragma unroll
    for (int l = 0; l < 50; ++l) len += (row[l] != 0) ? 1 : 0;
    lens[n] = len;
    rowmap[n] = n * LP + (len - 2);
    out_target[n] = (float)row[len - 1];
    out_utype[n] = u_type[b];
}

// ---------------- c_hist gather (must run before ha is reused) ----------------
__global__ void chist_kernel(const float* __restrict__ ha, const int* __restrict__ uid,
                             float* __restrict__ chist) {
    int n = blockIdx.x, d = threadIdx.x;
    chist[(size_t)n * 128 + d] = ha[(size_t)(N_ITEMS_C + uid[n & 255]) * 128 + d];
}

// ---------------- token embedding gather ----------------
__global__ void h0_gather_kernel(const float* __restrict__ id_emb, const int* __restrict__ ids,
                                 const int* __restrict__ lens, float* __restrict__ h0) {
    int g = blockIdx.x, d = threadIdx.x;
    int n = g / LP;
    int tt = g - n * LP;
    int len = lens[n];
    int b = n & 255, s = n >> 8;
    int id = (tt < len - 1) ? ids[(size_t)(b * 4 + s) * 50 + tt] : 0;
    h0[(size_t)g * 128 + d] = id_emb[(size_t)id * 128 + d];
}

// ---------------- fused GRU cell over all tokens (in-place on h) ----------------
// LDS: m_s 16KB + h_s 8KB + w_s 33.3KB = 57.9KB (<64KB/WG)
// Gate loop FULLY UNROLLED: gi_g/gh_g must be compile-time-indexed -> VGPRs,
// not scratch. (Rolled loop put 48 f32/thread in scratch: 282MB WRITE_SIZE.)
__global__ __launch_bounds__(256, 2) void gru_kernel(
    const float* __restrict__ hEi, const float* __restrict__ hEo,
    float* __restrict__ h, const int* __restrict__ lens,
    const float* __restrict__ w_ih, const float* __restrict__ w_hh,
    const float* __restrict__ b_ih, const float* __restrict__ b_hh,
    const float* __restrict__ b_iah, const float* __restrict__ b_oah)
{
    __shared__ float m_s[16][256];
    __shared__ float h_s[16][128];
    __shared__ __align__(8) bf16 w_s[128][130];   // one 128x128 bf16 tile, odd dword stride
    const int tid = threadIdx.x;
    const int g0 = blockIdx.x * 16;

    for (int i = 0; i < 16; ++i) {
        int id = i * 256 + tid;
        int t = id >> 8, k = id & 255;
        int g = g0 + t;
        int n = g / LP;
        int tt = g - n * LP;
        int len = lens[n];
        float v;
        if (k < 128) {
            v = b_iah[k];
            if (tt >= 1 && tt < len - 1) v += hEi[(size_t)(g - 1) * 128 + k];
        } else {
            int kk = k - 128;
            v = b_oah[kk];
            if (tt < len - 2) v += hEo[(size_t)(g + 1) * 128 + kk];
        }
        m_s[t][k] = v;
    }
    for (int i = 0; i < 8; ++i) {
        int id = i * 256 + tid;
        int t = id >> 7, k = id & 127;
        h_s[t][k] = h[(size_t)(g0 + t) * 128 + k];
    }

    const int jj = tid & 127;
    const int tg = (tid >> 7) * 8;
    float gi_g[3][8], gh_g[3][8];

#pragma unroll
    for (int c = 0; c < 3; ++c) {
        float ai[8] = {0, 0, 0, 0, 0, 0, 0, 0};
        // --- two K-halves of w_ih chunk c ---
#pragma unroll
        for (int p = 0; p < 2; ++p) {
            __syncthreads();    // staging-data ready fence from prior phase / initial stage
            {
                const float2* wg = (const float2*)(w_ih + (size_t)c * 32768);
                for (int i = 0; i < 32; ++i) {
                    int d2 = i * 256 + tid;              // 8192 pairs: 128 rows x 64 pairs
                    int jr = d2 >> 6, pi = d2 & 63;
                    float2 w = wg[(size_t)jr * 128 + p * 64 + pi];
                    *(uint32*)&w_s[jr][pi * 2] = packbf(w.x, w.y);
                }
            }
            __syncthreads();
            for (int k2 = 0; k2 < 64; ++k2) {
                uint32 wp = *(const uint32*)&w_s[jj][k2 * 2];
                float w0 = bflo(wp), w1 = bfhi(wp);
#pragma unroll
                for (int u = 0; u < 8; ++u) {
                    float2 m2 = *(const float2*)&m_s[tg + u][p * 128 + k2 * 2];
                    ai[u] += m2.x * w0 + m2.y * w1;
                }
            }
        }
        // --- w_hh chunk c ---
        __syncthreads();
        {
            const float2* wg2 = (const float2*)(w_hh + (size_t)c * 16384);
            for (int i = 0; i < 32; ++i) {
                int d2 = i * 256 + tid;                  // 8192 pairs: 128 rows x 64 pairs
                int jr = d2 >> 6, pi = d2 & 63;
                float2 w = wg2[(size_t)jr * 64 + pi];
                *(uint32*)&w_s[jr][pi * 2] = packbf(w.x, w.y);
            }
        }
        __syncthreads();
        float ah[8] = {0, 0, 0, 0, 0, 0, 0, 0};
        for (int k2 = 0; k2 < 64; ++k2) {
            uint32 wp = *(const uint32*)&w_s[jj][k2 * 2];
            float w0 = bflo(wp), w1 = bfhi(wp);
#pragma unroll
            for (int u = 0; u < 8; ++u) {
                float2 h2 = *(const float2*)&h_s[tg + u][k2 * 2];
                ah[u] += h2.x * w0 + h2.y * w1;
            }
        }
        float bi = b_ih[c * 128 + jj];
        float bh = b_hh[c * 128 + jj];
#pragma unroll
        for (int u = 0; u < 8; ++u) {
            gi_g[c][u] = ai[u] + bi;
            gh_g[c][u] = ah[u] + bh;
        }
    }
#pragma unroll
    for (int u = 0; u < 8; ++u) {
        int t = tg + u;
        float ho = h_s[t][jj];
        float rg = 1.f / (1.f + expf(-(gi_g[0][u] + gh_g[0][u])));
        float zg = 1.f / (1.f + expf(-(gi_g[1][u] + gh_g[1][u])));
        float ng = tanhf(gi_g[2][u] + rg * gh_g[2][u]);
        h[(size_t)(g0 + t) * 128 + jj] = ng + zg * (ho - ng);
    }
}

// ---------------- attention readout + fuse layer -> reps (f32 out) ----------------
__global__ __launch_bounds__(128) void attn_fuse_kernel(
    const float* __restrict__ q1h, const float* __restrict__ q2h,
    const float* __restrict__ h, const float* __restrict__ chist,
    const int* __restrict__ lens, const float* __restrict__ att_w,
    const float* __restrict__ fuse_w, const float* __restrict__ fuse_b,
    float* __restrict__ out)
{
    __shared__ float q1s[128], aws[128], al[64], cv[256];
    const int n = blockIdx.x, tid = threadIdx.x;
    q1s[tid] = q1h[(size_t)n * 128 + tid];
    aws[tid] = att_w[tid];
    if (tid < 64) al[tid] = 0.f;
    __syncthreads();
    const int len = lens[n];
    if (tid < len - 1) {
        const float* q2 = &q2h[(size_t)(n * LP + tid) * 128];
        float s = 0.f;
        for (int d = 0; d < 128; ++d) {
            float x = q1s[d] + q2[d];
            s += aws[d] / (1.f + expf(-x));
        }
        al[tid] = s;
    }
    __syncthreads();
    float ssum = 0.f;
    for (int t = 0; t < len - 1; ++t) ssum += al[t];
    float inv = 1.f / (ssum + 1e-8f);
    float c = 0.f;
    for (int t = 0; t < len - 1; ++t)
        c += al[t] * inv * h[(size_t)(n * LP + t) * 128 + tid];
    cv[tid] = c;
    cv[128 + tid] = chist[(size_t)n * 128 + tid];
    __syncthreads();
    float s = fuse_b[tid];
    const float* fr = fuse_w + (size_t)tid * 256;
    for (int k = 0; k < 256; ++k) s += cv[k] * fr[k];
    out[(size_t)n * 128 + tid] = s;
}

// ============================================================================
extern "C" void kernel_launch(void* const* d_in, const int* in_sizes, int n_in,
                              void* d_out, int out_size, void* d_ws, size_t ws_size,
                              hipStream_t stream)
{
    const float* id_emb   = (const float*)d_in[0];
    const float* user_emb = (const float*)d_in[1];
    const float* lin_r_w  = (const float*)d_in[2];
    const float* upi_w    = (const float*)d_in[3];
    const float* upi_b    = (const float*)d_in[4];
    const float* upu_w    = (const float*)d_in[5];
    const float* upu_b    = (const float*)d_in[6];
    const float* w_ih     = (const float*)d_in[7];
    const float* w_hh     = (const float*)d_in[8];
    const float* b_ih     = (const float*)d_in[9];
    const float* b_hh     = (const float*)d_in[10];
    const float* b_iah    = (const float*)d_in[11];
    const float* b_oah    = (const float*)d_in[12];
    const float* ei_w     = (const float*)d_in[13];
    const float* ei_b     = (const float*)d_in[14];
    const float* eo_w     = (const float*)d_in[15];
    const float* eo_b     = (const float*)d_in[16];
    const float* q1_w     = (const float*)d_in[17];
    const float* q2_w     = (const float*)d_in[18];
    const float* att_w    = (const float*)d_in[19];
    const float* fuse_w   = (const float*)d_in[20];
    const float* fuse_b   = (const float*)d_in[21];
    const int*  rel_rows  = (const int*)d_in[22];
    const int*  rel_cols  = (const int*)d_in[23];
    const float* rel_vals = (const float*)d_in[24];
    const int*  ids       = (const int*)d_in[25];
    const int*  uid       = (const int*)d_in[26];
    const float* u_type   = (const float*)d_in[27];
    float* out = (float*)d_out;   // f32 outputs: reps[131072] | target[1024] | u_type[1024]

    float* ha    = (float*)d_ws;          // 8,960,000 f  (node features, f32)
    float* bufA  = ha   + 8960000;        // 8,960,000 f  (Wh, then h tokens)
    float* bufB  = bufA + 8960000;        // 8,960,000 f  (msg, then hEi, then q2h)
    float* q1h   = bufB + 8960000;        // 131,072 f
    float* chist = q1h  + 131072;         // 131,072 f
    int*   lens  = (int*)(chist + 131072);// 1024
    int*   rowmap= lens + 1024;           // 1024
    if (ws_size < (size_t)27144192 * 4 + 4096) return;  // ~108.6 MB needed

    // ---- global HGNN ----
    init_ha_kernel<<<8750, 256, 0, stream>>>((const float4*)id_emb, (const float4*)user_emb,
                                             (float4*)ha);
    for (int k = 0; k < 2; ++k) {
        hipMemsetAsync(bufB, 0, (size_t)8960000 * 4, stream);
        for (int r = 0; r < 3; ++r) {
            gemm128_kernel<<<1094, 256, 0, stream>>>(ha, nullptr, nullptr,
                lin_r_w + (size_t)(k * 3 + r) * 16384, nullptr, bufA, N_NODES_C, 0);
            scatter_kernel<<<NNZ_C / 2, 256, 0, stream>>>(bufA, bufB,
                rel_rows + (size_t)r * NNZ_C, rel_cols + (size_t)r * NNZ_C,
                rel_vals + (size_t)r * NNZ_C);
        }
        gemm128_kernel<<<782, 256, 0, stream>>>(bufB, ha, nullptr,
            upi_w + (size_t)k * 16384, upi_b + k * 128, ha, N_ITEMS_C, 1);
        gemm128_kernel<<<313, 256, 0, stream>>>(bufB + (size_t)N_ITEMS_C * 128,
            ha + (size_t)N_ITEMS_C * 128, nullptr,
            upu_w + (size_t)k * 16384, upu_b + k * 128, ha + (size_t)N_ITEMS_C * 128, N_USERS_C, 1);
    }

    // ---- session branch ----
    session_prep_kernel<<<4, 256, 0, stream>>>(ids, uid, u_type, lens, rowmap,
        out + 131072, out + 132096);
    chist_kernel<<<NSESS, 128, 0, stream>>>(ha, uid, chist);     // before ha is reused!
    h0_gather_kernel<<<NTOK, 128, 0, stream>>>(id_emb, ids, lens, bufA);
    gemm128_kernel<<<784, 256, 0, stream>>>(bufA, nullptr, nullptr, ei_w, ei_b, bufB, NTOK, 0);
    gemm128_kernel<<<784, 256, 0, stream>>>(bufA, nullptr, nullptr, eo_w, eo_b, ha, NTOK, 0);
    gru_kernel<<<NTOK / 16, 256, 0, stream>>>(bufB, ha, bufA, lens,
        w_ih, w_hh, b_ih, b_hh, b_iah, b_oah);
    gemm128_kernel<<<784, 256, 0, stream>>>(bufA, nullptr, nullptr, q2_w, nullptr, bufB, NTOK, 0);
    gemm128_kernel<<<16, 256, 0, stream>>>(bufA, nullptr, rowmap, q1_w, nullptr, q1h, NSESS, 0);
    attn_fuse_kernel<<<NSESS, 128, 0, stream>>>(q1h, bufB, bufA, chist, lens,
        att_w, fuse_w, fuse_b, out);
}

// Round 5
// 2136.366 us; speedup vs baseline: 1.8059x; 1.5750x over previous
//
#include <hip/hip_runtime.h>
#include <hip/hip_bf16.h>

typedef __hip_bfloat16 bf16;
typedef unsigned int uint32;

#define N_ITEMS_C 50000
#define N_USERS_C 20000
#define N_NODES_C 70000
#define NNZ_C 800000
#define NSESS 1024
#define LP 49
#define NTOK (NSESS * LP)   // 50176

__device__ __forceinline__ float bflo(uint32 u) { return __uint_as_float(u << 16); }
__device__ __forceinline__ float bfhi(uint32 u) { return __uint_as_float(u & 0xffff0000u); }
__device__ __forceinline__ uint32 packbf(float a, float b) {
    return (uint32)__bfloat16_as_ushort(__float2bfloat16(a)) |
           ((uint32)__bfloat16_as_ushort(__float2bfloat16(b)) << 16);
}

// ---------------- init: ha = concat(id_emb, user_emb) f32 copy ----------------
__global__ void init_ha_kernel(const float4* __restrict__ idq, const float4* __restrict__ usq,
                               float4* __restrict__ ha4) {
    int i = blockIdx.x * 256 + threadIdx.x;           // float4 index, 2,240,000 total
    ha4[i] = (i < 1600000) ? idq[i] : usq[i - 1600000];
}

// ---------------- generic GEMM: out[M,128] = op(A[M,128] @ W[128,128]^T + bias) ----
__global__ __launch_bounds__(256, 3) void gemm128_kernel(
    const float* __restrict__ A, const float* __restrict__ A2,
    const int* __restrict__ rowmap,
    const float* __restrict__ W, const float* __restrict__ bias,
    float* __restrict__ out, int M, int relu)
{
    __shared__ float As[128][65];               // [k][m]
    __shared__ __align__(8) bf16 Ws[128][66];   // [n][k-half]
    const int tid = threadIdx.x;
    const int row0 = blockIdx.x * 64;
#pragma unroll
    for (int i = 0; i < 8; ++i) {
        int id = i * 256 + tid;
        int r = id >> 5;
        int c4 = (id & 31) << 2;
        float4 v = make_float4(0.f, 0.f, 0.f, 0.f);
        int gr = row0 + r;
        if (gr < M) {
            int ar = rowmap ? rowmap[gr] : gr;
            v = *(const float4*)&A[(size_t)ar * 128 + c4];
            if (A2) {
                float4 w = *(const float4*)&A2[(size_t)ar * 128 + c4];
                v.x += w.x; v.y += w.y; v.z += w.z; v.w += w.w;
            }
        }
        As[c4 + 0][r] = v.x; As[c4 + 1][r] = v.y; As[c4 + 2][r] = v.z; As[c4 + 3][r] = v.w;
    }
    const int m0 = (tid & 15) * 4;
    const int n0 = (tid >> 4) * 8;
    float acc[4][8];
#pragma unroll
    for (int i = 0; i < 4; ++i)
#pragma unroll
        for (int j = 0; j < 8; ++j) acc[i][j] = 0.f;

    for (int p = 0; p < 2; ++p) {
        if (p) __syncthreads();
#pragma unroll
        for (int i = 0; i < 8; ++i) {
            int id = i * 256 + tid;
            int n = id >> 4, koff = (id & 15) * 4;
            float4 w = *(const float4*)&W[(size_t)n * 128 + p * 64 + koff];
            *(uint32*)&Ws[n][koff]     = packbf(w.x, w.y);
            *(uint32*)&Ws[n][koff + 2] = packbf(w.z, w.w);
        }
        __syncthreads();
        for (int k2 = 0; k2 < 32; ++k2) {
            int kk = p * 64 + 2 * k2;
            float av0[4], av1[4];
#pragma unroll
            for (int i = 0; i < 4; ++i) { av0[i] = As[kk][m0 + i]; av1[i] = As[kk + 1][m0 + i]; }
#pragma unroll
            for (int j = 0; j < 8; ++j) {
                uint32 wp = *(const uint32*)&Ws[n0 + j][2 * k2];
                float w0 = bflo(wp), w1 = bfhi(wp);
#pragma unroll
                for (int i = 0; i < 4; ++i)
                    acc[i][j] = fmaf(av1[i], w1, fmaf(av0[i], w0, acc[i][j]));
            }
        }
    }
    float bv[8];
#pragma unroll
    for (int j = 0; j < 8; ++j) bv[j] = bias ? bias[n0 + j] : 0.f;
#pragma unroll
    for (int i = 0; i < 4; ++i) {
        int r = row0 + m0 + i;
        if (r < M) {
            float vv[8];
#pragma unroll
            for (int j = 0; j < 8; ++j) {
                float v = acc[i][j] + bv[j];
                vv[j] = relu ? fmaxf(v, 0.f) : v;
            }
            *(float4*)&out[(size_t)r * 128 + n0] = make_float4(vv[0], vv[1], vv[2], vv[3]);
            *(float4*)&out[(size_t)r * 128 + n0 + 4] = make_float4(vv[4], vv[5], vv[6], vv[7]);
        }
    }
}

// ---------------- CSR build: count -> scan -> fill ----------------
__global__ __launch_bounds__(256) void csr_count_kernel(
    const int* __restrict__ rel_rows, int* __restrict__ offs)
{
    int r = blockIdx.y;
    int e = blockIdx.x * 256 + threadIdx.x;
    int row = rel_rows[(size_t)r * NNZ_C + e];
    atomicAdd(&offs[(size_t)r * 70001 + row + 1], 1);
}

__global__ __launch_bounds__(1024) void scan_kernel(int* __restrict__ offs) {
    __shared__ int s[1024];
    int* a = offs + (size_t)blockIdx.x * 70001;
    const int tid = threadIdx.x;
    int carry = 0;
    for (int base = 0; base < 70001; base += 1024) {
        int i = base + tid;
        int x = (i < 70001) ? a[i] : 0;
        s[tid] = x;
        __syncthreads();
        for (int d = 1; d < 1024; d <<= 1) {
            int t = (tid >= d) ? s[tid - d] : 0;
            __syncthreads();
            s[tid] += t;
            __syncthreads();
        }
        if (i < 70001) a[i] = s[tid] + carry;
        carry += s[1023];
        __syncthreads();
    }
}

__global__ __launch_bounds__(256) void csr_fill_kernel(
    const int* __restrict__ rel_rows, const int* __restrict__ rel_cols,
    const float* __restrict__ rel_vals, const int* __restrict__ offs,
    int* __restrict__ cur, int* __restrict__ colv, unsigned short* __restrict__ valv)
{
    int r = blockIdx.y;
    int e = blockIdx.x * 256 + threadIdx.x;
    size_t rb = (size_t)r * NNZ_C;
    int row = rel_rows[rb + e];
    int slot = offs[(size_t)r * 70001 + row] + atomicAdd(&cur[(size_t)r * 70000 + row], 1);
    colv[rb + slot] = rel_cols[rb + e];
    valv[rb + slot] = __bfloat16_as_ushort(__float2bfloat16(rel_vals[rb + e]));
}

// ---------------- gather: t_r[row] = sum_e val * ha[col]  (wave per row, no atomics) ----
__global__ __launch_bounds__(256) void gather_kernel(
    const float* __restrict__ ha, const int* __restrict__ colv,
    const unsigned short* __restrict__ valv, const int* __restrict__ offs,
    uint32* __restrict__ T)   // bf16 pairs, row stride 192 u32 (384 bf16)
{
    const int r = blockIdx.y;
    const int row = blockIdx.x * 4 + (threadIdx.x >> 6);
    const int lane = threadIdx.x & 63;
    const int* __restrict__ cv = colv + (size_t)r * NNZ_C;
    const unsigned short* __restrict__ vv = valv + (size_t)r * NNZ_C;
    const int* __restrict__ of = offs + (size_t)r * 70001;
    int e0 = of[row], e1 = of[row + 1];
    float ax = 0.f, ay = 0.f;
    int e = e0;
    for (; e + 2 <= e1; e += 2) {
        int c0 = cv[e], c1 = cv[e + 1];
        float v0 = __uint_as_float((uint32)vv[e] << 16);
        float v1 = __uint_as_float((uint32)vv[e + 1] << 16);
        float2 h0 = *(const float2*)&ha[(size_t)c0 * 128 + lane * 2];
        float2 h1 = *(const float2*)&ha[(size_t)c1 * 128 + lane * 2];
        ax += v0 * h0.x + v1 * h1.x;
        ay += v0 * h0.y + v1 * h1.y;
    }
    if (e < e1) {
        int c0 = cv[e];
        float v0 = __uint_as_float((uint32)vv[e] << 16);
        float2 h0 = *(const float2*)&ha[(size_t)c0 * 128 + lane * 2];
        ax += v0 * h0.x; ay += v0 * h0.y;
    }
    T[(size_t)row * 192 + r * 64 + lane] = packbf(ax, ay);
}

// ---------------- weight prep: V[which] = U @ W_r  (transposed-W staging) ----------------
__global__ __launch_bounds__(256, 3) void wprep_kernel(
    const float* __restrict__ upi_w, const float* __restrict__ upu_w,
    const float* __restrict__ lin_r_w, int k, float* __restrict__ Vbuf)
{
    __shared__ float As[128][65];
    __shared__ __align__(8) bf16 Ws[128][66];
    const int which = blockIdx.y, seg = which / 3, r = which % 3;
    const float* U  = (seg == 0 ? upi_w : upu_w) + (size_t)k * 16384;
    const float* Wr = lin_r_w + (size_t)(k * 3 + r) * 16384;
    float* out = Vbuf + (size_t)which * 16384;
    const int tid = threadIdx.x;
    const int row0 = blockIdx.x * 64;
#pragma unroll
    for (int i = 0; i < 8; ++i) {
        int id = i * 256 + tid;
        int rr = id >> 5, c4 = (id & 31) << 2;
        float4 v = *(const float4*)&U[(size_t)(row0 + rr) * 128 + c4];
        As[c4][rr] = v.x; As[c4+1][rr] = v.y; As[c4+2][rr] = v.z; As[c4+3][rr] = v.w;
    }
    const int m0 = (tid & 15) * 4;
    const int n0 = (tid >> 4) * 8;
    float acc[4][8];
#pragma unroll
    for (int i = 0; i < 4; ++i)
#pragma unroll
        for (int j = 0; j < 8; ++j) acc[i][j] = 0.f;
    for (int p = 0; p < 2; ++p) {
        if (p) __syncthreads();
        for (int i = 0; i < 32; ++i) {       // Ws[c][kf] = Wr[p*64+kf][c] (transposed)
            int id = i * 256 + tid;
            int c = id >> 6, kf = id & 63;
            Ws[c][kf] = __float2bfloat16(Wr[(size_t)(p * 64 + kf) * 128 + c]);
        }
        __syncthreads();
        for (int k2 = 0; k2 < 32; ++k2) {
            int kk = p * 64 + 2 * k2;
            float av0[4], av1[4];
#pragma unroll
            for (int i = 0; i < 4; ++i) { av0[i] = As[kk][m0 + i]; av1[i] = As[kk + 1][m0 + i]; }
#pragma unroll
            for (int j = 0; j < 8; ++j) {
                uint32 wp = *(const uint32*)&Ws[n0 + j][2 * k2];
                float w0 = bflo(wp), w1 = bfhi(wp);
#pragma unroll
                for (int i = 0; i < 4; ++i)
                    acc[i][j] = fmaf(av1[i], w1, fmaf(av0[i], w0, acc[i][j]));
            }
        }
    }
#pragma unroll
    for (int i = 0; i < 4; ++i) {
        int rr = row0 + m0 + i;
        *(float4*)&out[(size_t)rr * 128 + n0]     = make_float4(acc[i][0], acc[i][1], acc[i][2], acc[i][3]);
        *(float4*)&out[(size_t)rr * 128 + n0 + 4] = make_float4(acc[i][4], acc[i][5], acc[i][6], acc[i][7]);
    }
}

// ---------------- HGNN update: ha = relu([T | ha] @ [V0;V1;V2;U]^T + b), in place ----
__global__ __launch_bounds__(256, 3) void hgnn_update_kernel(
    const uint32* __restrict__ T, float* __restrict__ ha,
    const float* __restrict__ Vbuf, const float* __restrict__ U,
    const float* __restrict__ bias, int row0, int M)
{
    __shared__ float As[128][65];
    __shared__ __align__(8) bf16 Ws[128][66];
    const int tid = threadIdx.x;
    const int rbase = blockIdx.x * 64;
    const int m0 = (tid & 15) * 4;
    const int n0 = (tid >> 4) * 8;
    float acc[4][8];
#pragma unroll
    for (int i = 0; i < 4; ++i)
#pragma unroll
        for (int j = 0; j < 8; ++j) acc[i][j] = 0.f;

    for (int ph = 0; ph < 4; ++ph) {
        if (ph) __syncthreads();               // prior compute done before restaging As
        if (ph < 3) {
#pragma unroll
            for (int i = 0; i < 16; ++i) {     // 64 rows x 64 u32 of T-phase
                int id = i * 256 + tid;
                int rr = id >> 6, kq = id & 63;
                uint32 u = 0;
                if (rbase + rr < M)
                    u = T[(size_t)(row0 + rbase + rr) * 192 + ph * 64 + kq];
                As[kq * 2][rr]     = bflo(u);
                As[kq * 2 + 1][rr] = bfhi(u);
            }
        } else {
#pragma unroll
            for (int i = 0; i < 8; ++i) {      // ha-phase, f32
                int id = i * 256 + tid;
                int rr = id >> 5, c4 = (id & 31) << 2;
                float4 v = make_float4(0.f, 0.f, 0.f, 0.f);
                if (rbase + rr < M)
                    v = *(const float4*)&ha[(size_t)(row0 + rbase + rr) * 128 + c4];
                As[c4][rr] = v.x; As[c4+1][rr] = v.y; As[c4+2][rr] = v.z; As[c4+3][rr] = v.w;
            }
        }
        const float* Wp = (ph < 3) ? (Vbuf + (size_t)ph * 16384) : U;
        for (int p = 0; p < 2; ++p) {
            __syncthreads();                   // As ready / prior Ws reads done
#pragma unroll
            for (int i = 0; i < 8; ++i) {
                int id = i * 256 + tid;
                int n = id >> 4, koff = (id & 15) * 4;
                float4 w = *(const float4*)&Wp[(size_t)n * 128 + p * 64 + koff];
                *(uint32*)&Ws[n][koff]     = packbf(w.x, w.y);
                *(uint32*)&Ws[n][koff + 2] = packbf(w.z, w.w);
            }
            __syncthreads();
            for (int k2 = 0; k2 < 32; ++k2) {
                int kk = p * 64 + 2 * k2;
                float av0[4], av1[4];
#pragma unroll
                for (int i = 0; i < 4; ++i) { av0[i] = As[kk][m0 + i]; av1[i] = As[kk + 1][m0 + i]; }
#pragma unroll
                for (int j = 0; j < 8; ++j) {
                    uint32 wp = *(const uint32*)&Ws[n0 + j][2 * k2];
                    float w0 = bflo(wp), w1 = bfhi(wp);
#pragma unroll
                    for (int i = 0; i < 4; ++i)
                        acc[i][j] = fmaf(av1[i], w1, fmaf(av0[i], w0, acc[i][j]));
                }
            }
        }
    }
    float bv[8];
#pragma unroll
    for (int j = 0; j < 8; ++j) bv[j] = bias[n0 + j];
#pragma unroll
    for (int i = 0; i < 4; ++i) {
        int rr = rbase + m0 + i;
        if (rr < M) {
            float vv[8];
#pragma unroll
            for (int j = 0; j < 8; ++j) vv[j] = fmaxf(acc[i][j] + bv[j], 0.f);
            *(float4*)&ha[(size_t)(row0 + rr) * 128 + n0]     = make_float4(vv[0], vv[1], vv[2], vv[3]);
            *(float4*)&ha[(size_t)(row0 + rr) * 128 + n0 + 4] = make_float4(vv[4], vv[5], vv[6], vv[7]);
        }
    }
}

// ---------------- session prep ----------------
__global__ void session_prep_kernel(const int* __restrict__ ids, const int* __restrict__ uid,
                                    const float* __restrict__ u_type,
                                    int* __restrict__ lens, int* __restrict__ rowmap,
                                    float* __restrict__ out_target, float* __restrict__ out_utype)
{
    int n = blockIdx.x * 256 + threadIdx.x;
    if (n >= NSESS) return;
    int b = n & 255, s = n >> 8;
    const int* row = ids + (size_t)(b * 4 + s) * 50;
    int len = 0;
#pragma unroll
    for (int l = 0; l < 50; ++l) len += (row[l] != 0) ? 1 : 0;
    lens[n] = len;
    rowmap[n] = n * LP + (len - 2);
    out_target[n] = (float)row[len - 1];
    out_utype[n] = u_type[b];
}

// ---------------- c_hist gather (before ha region is reused) ----------------
__global__ void chist_kernel(const float* __restrict__ ha, const int* __restrict__ uid,
                             float* __restrict__ chist) {
    int n = blockIdx.x, d = threadIdx.x;
    chist[(size_t)n * 128 + d] = ha[(size_t)(N_ITEMS_C + uid[n & 255]) * 128 + d];
}

// ---------------- token embedding gather ----------------
__global__ void h0_gather_kernel(const float* __restrict__ id_emb, const int* __restrict__ ids,
                                 const int* __restrict__ lens, float* __restrict__ h0) {
    int g = blockIdx.x, d = threadIdx.x;
    int n = g / LP;
    int tt = g - n * LP;
    int len = lens[n];
    int b = n & 255, s = n >> 8;
    int id = (tt < len - 1) ? ids[(size_t)(b * 4 + s) * 50 + tt] : 0;
    h0[(size_t)g * 128 + d] = id_emb[(size_t)id * 128 + d];
}

// ---------------- fused GRU cell over all tokens (in-place on h) ----------------
__global__ __launch_bounds__(256, 2) void gru_kernel(
    const float* __restrict__ hEi, const float* __restrict__ hEo,
    float* __restrict__ h, const int* __restrict__ lens,
    const float* __restrict__ w_ih, const float* __restrict__ w_hh,
    const float* __restrict__ b_ih, const float* __restrict__ b_hh,
    const float* __restrict__ b_iah, const float* __restrict__ b_oah)
{
    __shared__ float m_s[16][256];
    __shared__ float h_s[16][128];
    __shared__ __align__(8) bf16 w_s[128][130];
    const int tid = threadIdx.x;
    const int g0 = blockIdx.x * 16;

    for (int i = 0; i < 16; ++i) {
        int id = i * 256 + tid;
        int t = id >> 8, k = id & 255;
        int g = g0 + t;
        int n = g / LP;
        int tt = g - n * LP;
        int len = lens[n];
        float v;
        if (k < 128) {
            v = b_iah[k];
            if (tt >= 1 && tt < len - 1) v += hEi[(size_t)(g - 1) * 128 + k];
        } else {
            int kk = k - 128;
            v = b_oah[kk];
            if (tt < len - 2) v += hEo[(size_t)(g + 1) * 128 + kk];
        }
        m_s[t][k] = v;
    }
    for (int i = 0; i < 8; ++i) {
        int id = i * 256 + tid;
        int t = id >> 7, k = id & 127;
        h_s[t][k] = h[(size_t)(g0 + t) * 128 + k];
    }

    const int jj = tid & 127;
    const int tg = (tid >> 7) * 8;
    float gi_g[3][8], gh_g[3][8];

#pragma unroll
    for (int c = 0; c < 3; ++c) {
        float ai[8] = {0, 0, 0, 0, 0, 0, 0, 0};
#pragma unroll
        for (int p = 0; p < 2; ++p) {
            __syncthreads();
            {
                const float2* wg = (const float2*)(w_ih + (size_t)c * 32768);
                for (int i = 0; i < 32; ++i) {
                    int d2 = i * 256 + tid;
                    int jr = d2 >> 6, pi = d2 & 63;
                    float2 w = wg[(size_t)jr * 128 + p * 64 + pi];
                    *(uint32*)&w_s[jr][pi * 2] = packbf(w.x, w.y);
                }
            }
            __syncthreads();
            for (int k2 = 0; k2 < 64; ++k2) {
                uint32 wp = *(const uint32*)&w_s[jj][k2 * 2];
                float w0 = bflo(wp), w1 = bfhi(wp);
#pragma unroll
                for (int u = 0; u < 8; ++u) {
                    float2 m2 = *(const float2*)&m_s[tg + u][p * 128 + k2 * 2];
                    ai[u] += m2.x * w0 + m2.y * w1;
                }
            }
        }
        __syncthreads();
        {
            const float2* wg2 = (const float2*)(w_hh + (size_t)c * 16384);
            for (int i = 0; i < 32; ++i) {
                int d2 = i * 256 + tid;
                int jr = d2 >> 6, pi = d2 & 63;
                float2 w = wg2[(size_t)jr * 64 + pi];
                *(uint32*)&w_s[jr][pi * 2] = packbf(w.x, w.y);
            }
        }
        __syncthreads();
        float ah[8] = {0, 0, 0, 0, 0, 0, 0, 0};
        for (int k2 = 0; k2 < 64; ++k2) {
            uint32 wp = *(const uint32*)&w_s[jj][k2 * 2];
            float w0 = bflo(wp), w1 = bfhi(wp);
#pragma unroll
            for (int u = 0; u < 8; ++u) {
                float2 h2 = *(const float2*)&h_s[tg + u][k2 * 2];
                ah[u] += h2.x * w0 + h2.y * w1;
            }
        }
        float bi = b_ih[c * 128 + jj];
        float bh = b_hh[c * 128 + jj];
#pragma unroll
        for (int u = 0; u < 8; ++u) {
            gi_g[c][u] = ai[u] + bi;
            gh_g[c][u] = ah[u] + bh;
        }
    }
#pragma unroll
    for (int u = 0; u < 8; ++u) {
        int t = tg + u;
        float ho = h_s[t][jj];
        float rg = 1.f / (1.f + expf(-(gi_g[0][u] + gh_g[0][u])));
        float zg = 1.f / (1.f + expf(-(gi_g[1][u] + gh_g[1][u])));
        float ng = tanhf(gi_g[2][u] + rg * gh_g[2][u]);
        h[(size_t)(g0 + t) * 128 + jj] = ng + zg * (ho - ng);
    }
}

// ---------------- attention readout + fuse layer -> reps (f32 out) ----------------
__global__ __launch_bounds__(128) void attn_fuse_kernel(
    const float* __restrict__ q1h, const float* __restrict__ q2h,
    const float* __restrict__ h, const float* __restrict__ chist,
    const int* __restrict__ lens, const float* __restrict__ att_w,
    const float* __restrict__ fuse_w, const float* __restrict__ fuse_b,
    float* __restrict__ out)
{
    __shared__ float q1s[128], aws[128], al[64], cv[256];
    const int n = blockIdx.x, tid = threadIdx.x;
    q1s[tid] = q1h[(size_t)n * 128 + tid];
    aws[tid] = att_w[tid];
    if (tid < 64) al[tid] = 0.f;
    __syncthreads();
    const int len = lens[n];
    if (tid < len - 1) {
        const float* q2 = &q2h[(size_t)(n * LP + tid) * 128];
        float s = 0.f;
        for (int d = 0; d < 128; ++d) {
            float x = q1s[d] + q2[d];
            s += aws[d] / (1.f + expf(-x));
        }
        al[tid] = s;
    }
    __syncthreads();
    float ssum = 0.f;
    for (int t = 0; t < len - 1; ++t) ssum += al[t];
    float inv = 1.f / (ssum + 1e-8f);
    float c = 0.f;
    for (int t = 0; t < len - 1; ++t)
        c += al[t] * inv * h[(size_t)(n * LP + t) * 128 + tid];
    cv[tid] = c;
    cv[128 + tid] = chist[(size_t)n * 128 + tid];
    __syncthreads();
    float s = fuse_b[tid];
    const float* fr = fuse_w + (size_t)tid * 256;
    for (int k = 0; k < 256; ++k) s += cv[k] * fr[k];
    out[(size_t)n * 128 + tid] = s;
}

// ============================================================================
extern "C" void kernel_launch(void* const* d_in, const int* in_sizes, int n_in,
                              void* d_out, int out_size, void* d_ws, size_t ws_size,
                              hipStream_t stream)
{
    const float* id_emb   = (const float*)d_in[0];
    const float* user_emb = (const float*)d_in[1];
    const float* lin_r_w  = (const float*)d_in[2];
    const float* upi_w    = (const float*)d_in[3];
    const float* upi_b    = (const float*)d_in[4];
    const float* upu_w    = (const float*)d_in[5];
    const float* upu_b    = (const float*)d_in[6];
    const float* w_ih     = (const float*)d_in[7];
    const float* w_hh     = (const float*)d_in[8];
    const float* b_ih     = (const float*)d_in[9];
    const float* b_hh     = (const float*)d_in[10];
    const float* b_iah    = (const float*)d_in[11];
    const float* b_oah    = (const float*)d_in[12];
    const float* ei_w     = (const float*)d_in[13];
    const float* ei_b     = (const float*)d_in[14];
    const float* eo_w     = (const float*)d_in[15];
    const float* eo_b     = (const float*)d_in[16];
    const float* q1_w     = (const float*)d_in[17];
    const float* q2_w     = (const float*)d_in[18];
    const float* att_w    = (const float*)d_in[19];
    const float* fuse_w   = (const float*)d_in[20];
    const float* fuse_b   = (const float*)d_in[21];
    const int*  rel_rows  = (const int*)d_in[22];
    const int*  rel_cols  = (const int*)d_in[23];
    const float* rel_vals = (const float*)d_in[24];
    const int*  ids       = (const int*)d_in[25];
    const int*  uid       = (const int*)d_in[26];
    const float* u_type   = (const float*)d_in[27];
    float* out = (float*)d_out;   // reps[131072] | target[1024] | u_type[1024]

    // ---- workspace layout (f32 units) ----
    float* ha    = (float*)d_ws;                        //  8,960,000 f (36 MB)
    uint32* T    = (uint32*)d_ws + 8960000;             // 13,440,000 u32 (bf16 t, stride 384)
    int*   colv  = (int*)d_ws + 22400000;               //  2,400,000
    unsigned short* valv = (unsigned short*)((int*)d_ws + 24800000); // 2.4M ushort
    int*   offs  = (int*)d_ws + 26000000;               //  3 x 70001 (+pad)
    int*   cur   = (int*)d_ws + 26210004;               //  3 x 70000
    float* Vbuf  = (float*)d_ws + 26420004;             //  6 x 16384
    float* q1h   = (float*)d_ws + 26518308;             //  131,072
    float* chist = (float*)d_ws + 26649380;             //  131,072
    int*   lens  = (int*)d_ws + 26780452;               //  1024
    int*   rowmap= (int*)d_ws + 26781476;               //  1024
    // session reuse (after HGNN): sess_h in ha region, Ei/Eo in T region
    float* sess_h  = ha;
    float* sess_Ei = (float*)d_ws + 8960000;
    float* sess_Eo = (float*)d_ws + 15382528;
    float* q2h     = sess_Ei;
    if (ws_size < (size_t)27144192 * 4 + 4096) return;

    // ---- CSR build (shared by both layers) ----
    init_ha_kernel<<<8750, 256, 0, stream>>>((const float4*)id_emb, (const float4*)user_emb,
                                             (float4*)ha);
    hipMemsetAsync(offs, 0, (size_t)(210004 + 210000) * 4, stream);
    csr_count_kernel<<<dim3(3125, 3), 256, 0, stream>>>(rel_rows, offs);
    scan_kernel<<<3, 1024, 0, stream>>>(offs);
    csr_fill_kernel<<<dim3(3125, 3), 256, 0, stream>>>(rel_rows, rel_cols, rel_vals,
                                                       offs, cur, colv, valv);

    // ---- HGNN: 2 layers, no atomics ----
    for (int k = 0; k < 2; ++k) {
        wprep_kernel<<<dim3(2, 6), 256, 0, stream>>>(upi_w, upu_w, lin_r_w, k, Vbuf);
        gather_kernel<<<dim3(17500, 3), 256, 0, stream>>>(ha, colv, valv, offs, T);
        hgnn_update_kernel<<<782, 256, 0, stream>>>(T, ha, Vbuf,
            upi_w + (size_t)k * 16384, upi_b + k * 128, 0, N_ITEMS_C);
        hgnn_update_kernel<<<313, 256, 0, stream>>>(T, ha, Vbuf + 3 * 16384,
            upu_w + (size_t)k * 16384, upu_b + k * 128, N_ITEMS_C, N_USERS_C);
    }

    // ---- session branch ----
    session_prep_kernel<<<4, 256, 0, stream>>>(ids, uid, u_type, lens, rowmap,
        out + 131072, out + 132096);
    chist_kernel<<<NSESS, 128, 0, stream>>>(ha, uid, chist);   // before sess_h overwrites ha!
    h0_gather_kernel<<<NTOK, 128, 0, stream>>>(id_emb, ids, lens, sess_h);
    gemm128_kernel<<<784, 256, 0, stream>>>(sess_h, nullptr, nullptr, ei_w, ei_b, sess_Ei, NTOK, 0);
    gemm128_kernel<<<784, 256, 0, stream>>>(sess_h, nullptr, nullptr, eo_w, eo_b, sess_Eo, NTOK, 0);
    gru_kernel<<<NTOK / 16, 256, 0, stream>>>(sess_Ei, sess_Eo, sess_h, lens,
        w_ih, w_hh, b_ih, b_hh, b_iah, b_oah);
    gemm128_kernel<<<784, 256, 0, stream>>>(sess_h, nullptr, nullptr, q2_w, nullptr, q2h, NTOK, 0);
    gemm128_kernel<<<16, 256, 0, stream>>>(sess_h, nullptr, rowmap, q1_w, nullptr, q1h, NSESS, 0);
    attn_fuse_kernel<<<NSESS, 128, 0, stream>>>(q1h, q2h, sess_h, chist, lens,
        att_w, fuse_w, fuse_b, out);
}

// Round 6
// 1716.612 us; speedup vs baseline: 2.2475x; 1.2445x over previous
//
#include <hip/hip_runtime.h>
#include <hip/hip_bf16.h>

typedef __hip_bfloat16 bf16;
typedef unsigned int uint32;
typedef __attribute__((ext_vector_type(8))) short short8;   // 8 bf16 (4 VGPRs)
typedef __attribute__((ext_vector_type(4))) float f32x4;

#define N_ITEMS_C 50000
#define N_USERS_C 20000
#define N_NODES_C 70000
#define NNZ_C 800000
#define NSESS 1024
#define LP 49
#define NTOK (NSESS * LP)   // 50176

__device__ __forceinline__ float bflo(uint32 u) { return __uint_as_float(u << 16); }
__device__ __forceinline__ float bfhi(uint32 u) { return __uint_as_float(u & 0xffff0000u); }
__device__ __forceinline__ uint32 packbf(float a, float b) {
    return (uint32)__bfloat16_as_ushort(__float2bfloat16(a)) |
           ((uint32)__bfloat16_as_ushort(__float2bfloat16(b)) << 16);
}

// ---------------- init: ha = concat(id_emb, user_emb) f32 copy ----------------
__global__ void init_ha_kernel(const float4* __restrict__ idq, const float4* __restrict__ usq,
                               float4* __restrict__ ha4) {
    int i = blockIdx.x * 256 + threadIdx.x;           // float4 index, 2,240,000 total
    ha4[i] = (i < 1600000) ? idq[i] : usq[i - 1600000];
}

// ---------------- generic GEMM: out[M,128] = op(A[M,128] @ W[128,128]^T + bias) ----
__global__ __launch_bounds__(256, 3) void gemm128_kernel(
    const float* __restrict__ A, const float* __restrict__ A2,
    const int* __restrict__ rowmap,
    const float* __restrict__ W, const float* __restrict__ bias,
    float* __restrict__ out, int M, int relu)
{
    __shared__ float As[128][65];               // [k][m]
    __shared__ __align__(8) bf16 Ws[128][66];   // [n][k-half]
    const int tid = threadIdx.x;
    const int row0 = blockIdx.x * 64;
#pragma unroll
    for (int i = 0; i < 8; ++i) {
        int id = i * 256 + tid;
        int r = id >> 5;
        int c4 = (id & 31) << 2;
        float4 v = make_float4(0.f, 0.f, 0.f, 0.f);
        int gr = row0 + r;
        if (gr < M) {
            int ar = rowmap ? rowmap[gr] : gr;
            v = *(const float4*)&A[(size_t)ar * 128 + c4];
            if (A2) {
                float4 w = *(const float4*)&A2[(size_t)ar * 128 + c4];
                v.x += w.x; v.y += w.y; v.z += w.z; v.w += w.w;
            }
        }
        As[c4 + 0][r] = v.x; As[c4 + 1][r] = v.y; As[c4 + 2][r] = v.z; As[c4 + 3][r] = v.w;
    }
    const int m0 = (tid & 15) * 4;
    const int n0 = (tid >> 4) * 8;
    float acc[4][8];
#pragma unroll
    for (int i = 0; i < 4; ++i)
#pragma unroll
        for (int j = 0; j < 8; ++j) acc[i][j] = 0.f;

    for (int p = 0; p < 2; ++p) {
        if (p) __syncthreads();
#pragma unroll
        for (int i = 0; i < 8; ++i) {
            int id = i * 256 + tid;
            int n = id >> 4, koff = (id & 15) * 4;
            float4 w = *(const float4*)&W[(size_t)n * 128 + p * 64 + koff];
            *(uint32*)&Ws[n][koff]     = packbf(w.x, w.y);
            *(uint32*)&Ws[n][koff + 2] = packbf(w.z, w.w);
        }
        __syncthreads();
        for (int k2 = 0; k2 < 32; ++k2) {
            int kk = p * 64 + 2 * k2;
            float av0[4], av1[4];
#pragma unroll
            for (int i = 0; i < 4; ++i) { av0[i] = As[kk][m0 + i]; av1[i] = As[kk + 1][m0 + i]; }
#pragma unroll
            for (int j = 0; j < 8; ++j) {
                uint32 wp = *(const uint32*)&Ws[n0 + j][2 * k2];
                float w0 = bflo(wp), w1 = bfhi(wp);
#pragma unroll
                for (int i = 0; i < 4; ++i)
                    acc[i][j] = fmaf(av1[i], w1, fmaf(av0[i], w0, acc[i][j]));
            }
        }
    }
    float bv[8];
#pragma unroll
    for (int j = 0; j < 8; ++j) bv[j] = bias ? bias[n0 + j] : 0.f;
#pragma unroll
    for (int i = 0; i < 4; ++i) {
        int r = row0 + m0 + i;
        if (r < M) {
            float vv[8];
#pragma unroll
            for (int j = 0; j < 8; ++j) {
                float v = acc[i][j] + bv[j];
                vv[j] = relu ? fmaxf(v, 0.f) : v;
            }
            *(float4*)&out[(size_t)r * 128 + n0] = make_float4(vv[0], vv[1], vv[2], vv[3]);
            *(float4*)&out[(size_t)r * 128 + n0 + 4] = make_float4(vv[4], vv[5], vv[6], vv[7]);
        }
    }
}

// ---------------- CSR build: count -> scan -> fill ----------------
__global__ __launch_bounds__(256) void csr_count_kernel(
    const int* __restrict__ rel_rows, int* __restrict__ offs)
{
    int r = blockIdx.y;
    int e = blockIdx.x * 256 + threadIdx.x;
    int row = rel_rows[(size_t)r * NNZ_C + e];
    atomicAdd(&offs[(size_t)r * 70001 + row + 1], 1);
}

__global__ __launch_bounds__(1024) void scan_kernel(int* __restrict__ offs) {
    __shared__ int s[1024];
    int* a = offs + (size_t)blockIdx.x * 70001;
    const int tid = threadIdx.x;
    int carry = 0;
    for (int base = 0; base < 70001; base += 1024) {
        int i = base + tid;
        int x = (i < 70001) ? a[i] : 0;
        s[tid] = x;
        __syncthreads();
        for (int d = 1; d < 1024; d <<= 1) {
            int t = (tid >= d) ? s[tid - d] : 0;
            __syncthreads();
            s[tid] += t;
            __syncthreads();
        }
        if (i < 70001) a[i] = s[tid] + carry;
        carry += s[1023];
        __syncthreads();
    }
}

__global__ __launch_bounds__(256) void csr_fill_kernel(
    const int* __restrict__ rel_rows, const int* __restrict__ rel_cols,
    const float* __restrict__ rel_vals, const int* __restrict__ offs,
    int* __restrict__ cur, int* __restrict__ colv, unsigned short* __restrict__ valv)
{
    int r = blockIdx.y;
    int e = blockIdx.x * 256 + threadIdx.x;
    size_t rb = (size_t)r * NNZ_C;
    int row = rel_rows[rb + e];
    int slot = offs[(size_t)r * 70001 + row] + atomicAdd(&cur[(size_t)r * 70000 + row], 1);
    colv[rb + slot] = rel_cols[rb + e];
    valv[rb + slot] = __bfloat16_as_ushort(__float2bfloat16(rel_vals[rb + e]));
}

// ---------------- gather: t_r[row] = sum_e val * ha[col]  (wave per row, no atomics) ----
__global__ __launch_bounds__(256) void gather_kernel(
    const float* __restrict__ ha, const int* __restrict__ colv,
    const unsigned short* __restrict__ valv, const int* __restrict__ offs,
    uint32* __restrict__ T)   // bf16 pairs, row stride 192 u32 (384 bf16)
{
    const int r = blockIdx.y;
    const int row = blockIdx.x * 4 + (threadIdx.x >> 6);
    const int lane = threadIdx.x & 63;
    const int* __restrict__ cv = colv + (size_t)r * NNZ_C;
    const unsigned short* __restrict__ vv = valv + (size_t)r * NNZ_C;
    const int* __restrict__ of = offs + (size_t)r * 70001;
    int e0 = of[row], e1 = of[row + 1];
    float ax = 0.f, ay = 0.f;
    int e = e0;
    for (; e + 2 <= e1; e += 2) {
        int c0 = cv[e], c1 = cv[e + 1];
        float v0 = __uint_as_float((uint32)vv[e] << 16);
        float v1 = __uint_as_float((uint32)vv[e + 1] << 16);
        float2 h0 = *(const float2*)&ha[(size_t)c0 * 128 + lane * 2];
        float2 h1 = *(const float2*)&ha[(size_t)c1 * 128 + lane * 2];
        ax += v0 * h0.x + v1 * h1.x;
        ay += v0 * h0.y + v1 * h1.y;
    }
    if (e < e1) {
        int c0 = cv[e];
        float v0 = __uint_as_float((uint32)vv[e] << 16);
        float2 h0 = *(const float2*)&ha[(size_t)c0 * 128 + lane * 2];
        ax += v0 * h0.x; ay += v0 * h0.y;
    }
    T[(size_t)row * 192 + r * 64 + lane] = packbf(ax, ay);
}

// ---------------- weight prep: V[which] = U @ W_r  (transposed-W staging) ----------------
__global__ __launch_bounds__(256, 3) void wprep_kernel(
    const float* __restrict__ upi_w, const float* __restrict__ upu_w,
    const float* __restrict__ lin_r_w, int k, float* __restrict__ Vbuf)
{
    __shared__ float As[128][65];
    __shared__ __align__(8) bf16 Ws[128][66];
    const int which = blockIdx.y, seg = which / 3, r = which % 3;
    const float* U  = (seg == 0 ? upi_w : upu_w) + (size_t)k * 16384;
    const float* Wr = lin_r_w + (size_t)(k * 3 + r) * 16384;
    float* out = Vbuf + (size_t)which * 16384;
    const int tid = threadIdx.x;
    const int row0 = blockIdx.x * 64;
#pragma unroll
    for (int i = 0; i < 8; ++i) {
        int id = i * 256 + tid;
        int rr = id >> 5, c4 = (id & 31) << 2;
        float4 v = *(const float4*)&U[(size_t)(row0 + rr) * 128 + c4];
        As[c4][rr] = v.x; As[c4+1][rr] = v.y; As[c4+2][rr] = v.z; As[c4+3][rr] = v.w;
    }
    const int m0 = (tid & 15) * 4;
    const int n0 = (tid >> 4) * 8;
    float acc[4][8];
#pragma unroll
    for (int i = 0; i < 4; ++i)
#pragma unroll
        for (int j = 0; j < 8; ++j) acc[i][j] = 0.f;
    for (int p = 0; p < 2; ++p) {
        if (p) __syncthreads();
        for (int i = 0; i < 32; ++i) {       // Ws[c][kf] = Wr[p*64+kf][c] (transposed)
            int id = i * 256 + tid;
            int c = id >> 6, kf = id & 63;
            Ws[c][kf] = __float2bfloat16(Wr[(size_t)(p * 64 + kf) * 128 + c]);
        }
        __syncthreads();
        for (int k2 = 0; k2 < 32; ++k2) {
            int kk = p * 64 + 2 * k2;
            float av0[4], av1[4];
#pragma unroll
            for (int i = 0; i < 4; ++i) { av0[i] = As[kk][m0 + i]; av1[i] = As[kk + 1][m0 + i]; }
#pragma unroll
            for (int j = 0; j < 8; ++j) {
                uint32 wp = *(const uint32*)&Ws[n0 + j][2 * k2];
                float w0 = bflo(wp), w1 = bfhi(wp);
#pragma unroll
                for (int i = 0; i < 4; ++i)
                    acc[i][j] = fmaf(av1[i], w1, fmaf(av0[i], w0, acc[i][j]));
            }
        }
    }
#pragma unroll
    for (int i = 0; i < 4; ++i) {
        int rr = row0 + m0 + i;
        *(float4*)&out[(size_t)rr * 128 + n0]     = make_float4(acc[i][0], acc[i][1], acc[i][2], acc[i][3]);
        *(float4*)&out[(size_t)rr * 128 + n0 + 4] = make_float4(acc[i][4], acc[i][5], acc[i][6], acc[i][7]);
    }
}

// ---------------- HGNN update: ha = relu([T | ha] @ [V0;V1;V2;U]^T + b), in place ----
__global__ __launch_bounds__(256, 3) void hgnn_update_kernel(
    const uint32* __restrict__ T, float* __restrict__ ha,
    const float* __restrict__ Vbuf, const float* __restrict__ U,
    const float* __restrict__ bias, int row0, int M)
{
    __shared__ float As[128][65];
    __shared__ __align__(8) bf16 Ws[128][66];
    const int tid = threadIdx.x;
    const int rbase = blockIdx.x * 64;
    const int m0 = (tid & 15) * 4;
    const int n0 = (tid >> 4) * 8;
    float acc[4][8];
#pragma unroll
    for (int i = 0; i < 4; ++i)
#pragma unroll
        for (int j = 0; j < 8; ++j) acc[i][j] = 0.f;

    for (int ph = 0; ph < 4; ++ph) {
        if (ph) __syncthreads();
        if (ph < 3) {
#pragma unroll
            for (int i = 0; i < 16; ++i) {
                int id = i * 256 + tid;
                int rr = id >> 6, kq = id & 63;
                uint32 u = 0;
                if (rbase + rr < M)
                    u = T[(size_t)(row0 + rbase + rr) * 192 + ph * 64 + kq];
                As[kq * 2][rr]     = bflo(u);
                As[kq * 2 + 1][rr] = bfhi(u);
            }
        } else {
#pragma unroll
            for (int i = 0; i < 8; ++i) {
                int id = i * 256 + tid;
                int rr = id >> 5, c4 = (id & 31) << 2;
                float4 v = make_float4(0.f, 0.f, 0.f, 0.f);
                if (rbase + rr < M)
                    v = *(const float4*)&ha[(size_t)(row0 + rbase + rr) * 128 + c4];
                As[c4][rr] = v.x; As[c4+1][rr] = v.y; As[c4+2][rr] = v.z; As[c4+3][rr] = v.w;
            }
        }
        const float* Wp = (ph < 3) ? (Vbuf + (size_t)ph * 16384) : U;
        for (int p = 0; p < 2; ++p) {
            __syncthreads();
#pragma unroll
            for (int i = 0; i < 8; ++i) {
                int id = i * 256 + tid;
                int n = id >> 4, koff = (id & 15) * 4;
                float4 w = *(const float4*)&Wp[(size_t)n * 128 + p * 64 + koff];
                *(uint32*)&Ws[n][koff]     = packbf(w.x, w.y);
                *(uint32*)&Ws[n][koff + 2] = packbf(w.z, w.w);
            }
            __syncthreads();
            for (int k2 = 0; k2 < 32; ++k2) {
                int kk = p * 64 + 2 * k2;
                float av0[4], av1[4];
#pragma unroll
                for (int i = 0; i < 4; ++i) { av0[i] = As[kk][m0 + i]; av1[i] = As[kk + 1][m0 + i]; }
#pragma unroll
                for (int j = 0; j < 8; ++j) {
                    uint32 wp = *(const uint32*)&Ws[n0 + j][2 * k2];
                    float w0 = bflo(wp), w1 = bfhi(wp);
#pragma unroll
                    for (int i = 0; i < 4; ++i)
                        acc[i][j] = fmaf(av1[i], w1, fmaf(av0[i], w0, acc[i][j]));
                }
            }
        }
    }
    float bv[8];
#pragma unroll
    for (int j = 0; j < 8; ++j) bv[j] = bias[n0 + j];
#pragma unroll
    for (int i = 0; i < 4; ++i) {
        int rr = rbase + m0 + i;
        if (rr < M) {
            float vv[8];
#pragma unroll
            for (int j = 0; j < 8; ++j) vv[j] = fmaxf(acc[i][j] + bv[j], 0.f);
            *(float4*)&ha[(size_t)(row0 + rr) * 128 + n0]     = make_float4(vv[0], vv[1], vv[2], vv[3]);
            *(float4*)&ha[(size_t)(row0 + rr) * 128 + n0 + 4] = make_float4(vv[4], vv[5], vv[6], vv[7]);
        }
    }
}

// ---------------- session prep ----------------
__global__ void session_prep_kernel(const int* __restrict__ ids, const int* __restrict__ uid,
                                    const float* __restrict__ u_type,
                                    int* __restrict__ lens, int* __restrict__ rowmap,
                                    float* __restrict__ out_target, float* __restrict__ out_utype)
{
    int n = blockIdx.x * 256 + threadIdx.x;
    if (n >= NSESS) return;
    int b = n & 255, s = n >> 8;
    const int* row = ids + (size_t)(b * 4 + s) * 50;
    int len = 0;
#pragma unroll
    for (int l = 0; l < 50; ++l) len += (row[l] != 0) ? 1 : 0;
    lens[n] = len;
    rowmap[n] = n * LP + (len - 2);
    out_target[n] = (float)row[len - 1];
    out_utype[n] = u_type[b];
}

// ---------------- c_hist gather (before ha region is reused) ----------------
__global__ void chist_kernel(const float* __restrict__ ha, const int* __restrict__ uid,
                             float* __restrict__ chist) {
    int n = blockIdx.x, d = threadIdx.x;
    chist[(size_t)n * 128 + d] = ha[(size_t)(N_ITEMS_C + uid[n & 255]) * 128 + d];
}

// ---------------- token embedding gather ----------------
__global__ void h0_gather_kernel(const float* __restrict__ id_emb, const int* __restrict__ ids,
                                 const int* __restrict__ lens, float* __restrict__ h0) {
    int g = blockIdx.x, d = threadIdx.x;
    int n = g / LP;
    int tt = g - n * LP;
    int len = lens[n];
    int b = n & 255, s = n >> 8;
    int id = (tt < len - 1) ? ids[(size_t)(b * 4 + s) * 50 + tt] : 0;
    h0[(size_t)g * 128 + d] = id_emb[(size_t)id * 128 + d];
}

// ---------------- GRU weight pack: f32 -> bf16 row-major ----------------
__global__ __launch_bounds__(256) void gru_wpack_kernel(
    const float* __restrict__ w_ih, const float* __restrict__ w_hh,
    uint32* __restrict__ wihb, uint32* __restrict__ whhb)
{
    int id = blockIdx.x * 256 + threadIdx.x;   // pair index, 73728 total
    if (id < 49152) {
        float2 w = *(const float2*)&w_ih[(size_t)id * 2];
        wihb[id] = packbf(w.x, w.y);
    } else {
        int j = id - 49152;                    // 24576 pairs
        float2 w = *(const float2*)&w_hh[(size_t)j * 2];
        whhb[j] = packbf(w.x, w.y);
    }
}

// ---------------- MFMA GRU: gi = m @ w_ih^T, gh = h @ w_hh^T, fused gates ----------------
// Block = 16 tokens, 4 waves. Wave w covers cols c0=w*32..w*32+31 for all 3 gates.
// m (K=256) built on the fly from Ei/Eo + shift/mask/bias into LDS bf16.
__global__ __launch_bounds__(256, 2) void gru_mfma_kernel(
    const float* __restrict__ hEi, const float* __restrict__ hEo,
    float* __restrict__ h, const int* __restrict__ lens,
    const bf16* __restrict__ wihb,   // [384][256] bf16
    const bf16* __restrict__ whhb,   // [384][128] bf16
    const float* __restrict__ b_ih, const float* __restrict__ b_hh,
    const float* __restrict__ b_iah, const float* __restrict__ b_oah)
{
    __shared__ __align__(16) bf16 Agi[16][264];   // 16 rows x 256 k, pad 8 (stride 528B=33*16)
    __shared__ __align__(16) bf16 Agh[16][136];   // 16 rows x 128 k, pad 8 (stride 272B=17*16)
    const int tid = threadIdx.x;
    const int g0 = blockIdx.x * 16;

    // ---- stage A_gi: m[row][k] = (mask ? E[shifted] : 0) + bias, bf16 ----
#pragma unroll
    for (int i = 0; i < 8; ++i) {
        int p = i * 256 + tid;            // 2048 pairs = 16 rows x 128 pairs
        int row = p >> 7, kp = p & 127;
        int g = g0 + row;
        int n = g / LP;
        int tt = g - n * LP;
        int len = lens[n];
        int kk = (kp & 63) * 2;           // k within half
        float v0, v1;
        if (kp < 64) {                    // m_i half: Ei[g-1] if 1<=tt<len-1
            v0 = b_iah[kk]; v1 = b_iah[kk + 1];
            if (tt >= 1 && tt < len - 1) {
                float2 e = *(const float2*)&hEi[(size_t)(g - 1) * 128 + kk];
                v0 += e.x; v1 += e.y;
            }
        } else {                          // m_o half: Eo[g+1] if tt<len-2
            v0 = b_oah[kk]; v1 = b_oah[kk + 1];
            if (tt < len - 2) {
                float2 e = *(const float2*)&hEo[(size_t)(g + 1) * 128 + kk];
                v0 += e.x; v1 += e.y;
            }
        }
        *(uint32*)&Agi[row][kp * 2] = packbf(v0, v1);
    }
    // ---- stage A_gh: bf16(h) ----
#pragma unroll
    for (int i = 0; i < 4; ++i) {
        int p = i * 256 + tid;            // 1024 pairs = 16 rows x 64 pairs
        int row = p >> 6, kp = p & 63;
        float2 e = *(const float2*)&h[(size_t)(g0 + row) * 128 + kp * 2];
        *(uint32*)&Agh[row][kp * 2] = packbf(e.x, e.y);
    }
    __syncthreads();

    const int wv = tid >> 6;
    const int lane = tid & 63;
    const int quad = lane >> 4;
    const int lr = lane & 15;
    const int c0 = wv * 32;

    f32x4 accI[2][3], accH[2][3];
#pragma unroll
    for (int s = 0; s < 2; ++s)
#pragma unroll
        for (int gte = 0; gte < 3; ++gte) {
            accI[s][gte] = (f32x4){0.f, 0.f, 0.f, 0.f};
            accH[s][gte] = (f32x4){0.f, 0.f, 0.f, 0.f};
        }

    // ---- gi: K=256, 8 k-steps ----
#pragma unroll
    for (int ks = 0; ks < 8; ++ks) {
        short8 a = *(const short8*)&Agi[lr][ks * 32 + quad * 8];
#pragma unroll
        for (int s = 0; s < 2; ++s)
#pragma unroll
            for (int gte = 0; gte < 3; ++gte) {
                int n0 = gte * 128 + c0 + s * 16 + lr;
                short8 b = *(const short8*)&wihb[(size_t)n0 * 256 + ks * 32 + quad * 8];
                accI[s][gte] = __builtin_amdgcn_mfma_f32_16x16x32_bf16(a, b, accI[s][gte], 0, 0, 0);
            }
    }
    // ---- gh: K=128, 4 k-steps ----
#pragma unroll
    for (int ks = 0; ks < 4; ++ks) {
        short8 a = *(const short8*)&Agh[lr][ks * 32 + quad * 8];
#pragma unroll
        for (int s = 0; s < 2; ++s)
#pragma unroll
            for (int gte = 0; gte < 3; ++gte) {
                int n0 = gte * 128 + c0 + s * 16 + lr;
                short8 b = *(const short8*)&whhb[(size_t)n0 * 128 + ks * 32 + quad * 8];
                accH[s][gte] = __builtin_amdgcn_mfma_f32_16x16x32_bf16(a, b, accH[s][gte], 0, 0, 0);
            }
    }

    // ---- epilogue: gate math, in-place h update. C layout: col=lane&15, row=quad*4+reg ----
#pragma unroll
    for (int s = 0; s < 2; ++s) {
        int col = c0 + s * 16 + lr;
        float bir = b_ih[col], biz = b_ih[col + 128], bin = b_ih[col + 256];
        float bhr = b_hh[col], bhz = b_hh[col + 128], bhn = b_hh[col + 256];
#pragma unroll
        for (int reg = 0; reg < 4; ++reg) {
            int row = g0 + quad * 4 + reg;
            float gi_r = accI[s][0][reg] + bir, gh_r = accH[s][0][reg] + bhr;
            float gi_z = accI[s][1][reg] + biz, gh_z = accH[s][1][reg] + bhz;
            float gi_n = accI[s][2][reg] + bin, gh_n = accH[s][2][reg] + bhn;
            float rg = 1.f / (1.f + expf(-(gi_r + gh_r)));
            float zg = 1.f / (1.f + expf(-(gi_z + gh_z)));
            float ng = tanhf(gi_n + rg * gh_n);
            float ho = h[(size_t)row * 128 + col];
            h[(size_t)row * 128 + col] = ng + zg * (ho - ng);
        }
    }
}

// ---------------- attention readout + fuse layer -> reps (f32 out) ----------------
__global__ __launch_bounds__(128) void attn_fuse_kernel(
    const float* __restrict__ q1h, const float* __restrict__ q2h,
    const float* __restrict__ h, const float* __restrict__ chist,
    const int* __restrict__ lens, const float* __restrict__ att_w,
    const float* __restrict__ fuse_w, const float* __restrict__ fuse_b,
    float* __restrict__ out)
{
    __shared__ float q1s[128], aws[128], al[64], cv[256];
    const int n = blockIdx.x, tid = threadIdx.x;
    q1s[tid] = q1h[(size_t)n * 128 + tid];
    aws[tid] = att_w[tid];
    if (tid < 64) al[tid] = 0.f;
    __syncthreads();
    const int len = lens[n];
    if (tid < len - 1) {
        const float* q2 = &q2h[(size_t)(n * LP + tid) * 128];
        float s = 0.f;
        for (int d = 0; d < 128; ++d) {
            float x = q1s[d] + q2[d];
            s += aws[d] / (1.f + expf(-x));
        }
        al[tid] = s;
    }
    __syncthreads();
    float ssum = 0.f;
    for (int t = 0; t < len - 1; ++t) ssum += al[t];
    float inv = 1.f / (ssum + 1e-8f);
    float c = 0.f;
    for (int t = 0; t < len - 1; ++t)
        c += al[t] * inv * h[(size_t)(n * LP + t) * 128 + tid];
    cv[tid] = c;
    cv[128 + tid] = chist[(size_t)n * 128 + tid];
    __syncthreads();
    float s = fuse_b[tid];
    const float* fr = fuse_w + (size_t)tid * 256;
    for (int k = 0; k < 256; ++k) s += cv[k] * fr[k];
    out[(size_t)n * 128 + tid] = s;
}

// ============================================================================
extern "C" void kernel_launch(void* const* d_in, const int* in_sizes, int n_in,
                              void* d_out, int out_size, void* d_ws, size_t ws_size,
                              hipStream_t stream)
{
    const float* id_emb   = (const float*)d_in[0];
    const float* user_emb = (const float*)d_in[1];
    const float* lin_r_w  = (const float*)d_in[2];
    const float* upi_w    = (const float*)d_in[3];
    const float* upi_b    = (const float*)d_in[4];
    const float* upu_w    = (const float*)d_in[5];
    const float* upu_b    = (const float*)d_in[6];
    const float* w_ih     = (const float*)d_in[7];
    const float* w_hh     = (const float*)d_in[8];
    const float* b_ih     = (const float*)d_in[9];
    const float* b_hh     = (const float*)d_in[10];
    const float* b_iah    = (const float*)d_in[11];
    const float* b_oah    = (const float*)d_in[12];
    const float* ei_w     = (const float*)d_in[13];
    const float* ei_b     = (const float*)d_in[14];
    const float* eo_w     = (const float*)d_in[15];
    const float* eo_b     = (const float*)d_in[16];
    const float* q1_w     = (const float*)d_in[17];
    const float* q2_w     = (const float*)d_in[18];
    const float* att_w    = (const float*)d_in[19];
    const float* fuse_w   = (const float*)d_in[20];
    const float* fuse_b   = (const float*)d_in[21];
    const int*  rel_rows  = (const int*)d_in[22];
    const int*  rel_cols  = (const int*)d_in[23];
    const float* rel_vals = (const float*)d_in[24];
    const int*  ids       = (const int*)d_in[25];
    const int*  uid       = (const int*)d_in[26];
    const float* u_type   = (const float*)d_in[27];
    float* out = (float*)d_out;   // reps[131072] | target[1024] | u_type[1024]

    // ---- workspace layout (f32 units) ----
    float* ha    = (float*)d_ws;                        //  8,960,000 f (36 MB)
    uint32* T    = (uint32*)d_ws + 8960000;             // 13,440,000 u32 (bf16 t, stride 384)
    int*   colv  = (int*)d_ws + 22400000;               //  2,400,000
    unsigned short* valv = (unsigned short*)((int*)d_ws + 24800000); // 2.4M ushort
    int*   offs  = (int*)d_ws + 26000000;               //  3 x 70001 (+pad)
    int*   cur   = (int*)d_ws + 26210004;               //  3 x 70000
    float* Vbuf  = (float*)d_ws + 26420004;             //  6 x 16384 (HGNN); GRU wts after
    float* q1h   = (float*)d_ws + 26518308;             //  131,072
    float* chist = (float*)d_ws + 26649380;             //  131,072
    int*   lens  = (int*)d_ws + 26780452;               //  1024
    int*   rowmap= (int*)d_ws + 26781476;               //  1024
    // session reuse (after HGNN): sess_h in ha region, Ei/Eo in T region
    float* sess_h  = ha;
    float* sess_Ei = (float*)d_ws + 8960000;
    float* sess_Eo = (float*)d_ws + 15382528;
    float* q2h     = sess_Ei;
    // GRU bf16 weights overlay the (dead-after-HGNN) Vbuf region:
    uint32* wihb = (uint32*)Vbuf;                       // 49,152 u32 (384x256 bf16)
    uint32* whhb = wihb + 49152;                        // 24,576 u32 (384x128 bf16)
    if (ws_size < (size_t)27144192 * 4 + 4096) return;

    // ---- CSR build (shared by both layers) ----
    init_ha_kernel<<<8750, 256, 0, stream>>>((const float4*)id_emb, (const float4*)user_emb,
                                             (float4*)ha);
    hipMemsetAsync(offs, 0, (size_t)(210004 + 210000) * 4, stream);
    csr_count_kernel<<<dim3(3125, 3), 256, 0, stream>>>(rel_rows, offs);
    scan_kernel<<<3, 1024, 0, stream>>>(offs);
    csr_fill_kernel<<<dim3(3125, 3), 256, 0, stream>>>(rel_rows, rel_cols, rel_vals,
                                                       offs, cur, colv, valv);

    // ---- HGNN: 2 layers, no atomics ----
    for (int k = 0; k < 2; ++k) {
        wprep_kernel<<<dim3(2, 6), 256, 0, stream>>>(upi_w, upu_w, lin_r_w, k, Vbuf);
        gather_kernel<<<dim3(17500, 3), 256, 0, stream>>>(ha, colv, valv, offs, T);
        hgnn_update_kernel<<<782, 256, 0, stream>>>(T, ha, Vbuf,
            upi_w + (size_t)k * 16384, upi_b + k * 128, 0, N_ITEMS_C);
        hgnn_update_kernel<<<313, 256, 0, stream>>>(T, ha, Vbuf + 3 * 16384,
            upu_w + (size_t)k * 16384, upu_b + k * 128, N_ITEMS_C, N_USERS_C);
    }

    // ---- session branch ----
    session_prep_kernel<<<4, 256, 0, stream>>>(ids, uid, u_type, lens, rowmap,
        out + 131072, out + 132096);
    chist_kernel<<<NSESS, 128, 0, stream>>>(ha, uid, chist);   // before sess_h overwrites ha!
    h0_gather_kernel<<<NTOK, 128, 0, stream>>>(id_emb, ids, lens, sess_h);
    gemm128_kernel<<<784, 256, 0, stream>>>(sess_h, nullptr, nullptr, ei_w, ei_b, sess_Ei, NTOK, 0);
    gemm128_kernel<<<784, 256, 0, stream>>>(sess_h, nullptr, nullptr, eo_w, eo_b, sess_Eo, NTOK, 0);
    gru_wpack_kernel<<<288, 256, 0, stream>>>(w_ih, w_hh, wihb, whhb);   // Vbuf dead after HGNN
    gru_mfma_kernel<<<NTOK / 16, 256, 0, stream>>>(sess_Ei, sess_Eo, sess_h, lens,
        (const bf16*)wihb, (const bf16*)whhb, b_ih, b_hh, b_iah, b_oah);
    gemm128_kernel<<<784, 256, 0, stream>>>(sess_h, nullptr, nullptr, q2_w, nullptr, q2h, NTOK, 0);
    gemm128_kernel<<<16, 256, 0, stream>>>(sess_h, nullptr, rowmap, q1_w, nullptr, q1h, NSESS, 0);
    attn_fuse_kernel<<<NSESS, 128, 0, stream>>>(q1h, q2h, sess_h, chist, lens,
        att_w, fuse_w, fuse_b, out);
}

// Round 7
// 1285.647 us; speedup vs baseline: 3.0008x; 1.3352x over previous
//
#include <hip/hip_runtime.h>
#include <hip/hip_bf16.h>

typedef __hip_bfloat16 bf16;
typedef unsigned int uint32;
typedef __attribute__((ext_vector_type(8))) short short8;   // 8 bf16 (4 VGPRs)
typedef __attribute__((ext_vector_type(4))) float f32x4;

#define N_ITEMS_C 50000
#define N_USERS_C 20000
#define N_NODES_C 70000
#define NNZ_C 800000
#define NSESS 1024
#define LP 49
#define NTOK (NSESS * LP)   // 50176

__device__ __forceinline__ float bflo(uint32 u) { return __uint_as_float(u << 16); }
__device__ __forceinline__ float bfhi(uint32 u) { return __uint_as_float(u & 0xffff0000u); }
__device__ __forceinline__ uint32 packbf(float a, float b) {
    return (uint32)__bfloat16_as_ushort(__float2bfloat16(a)) |
           ((uint32)__bfloat16_as_ushort(__float2bfloat16(b)) << 16);
}

// ---------------- init: hab = bf16(concat(id_emb, user_emb)) ----------------
__global__ void init_hab_kernel(const float2* __restrict__ idp, const float2* __restrict__ usp,
                                uint32* __restrict__ hab) {
    int i = blockIdx.x * 256 + threadIdx.x;           // pair index, 4,480,000 total
    float2 w = (i < 3200000) ? idp[i] : usp[i - 3200000];
    hab[i] = packbf(w.x, w.y);
}

// ---------------- generic GEMM: out[M,128] = op(A[M,128] @ W[128,128]^T + bias) ----
__global__ __launch_bounds__(256, 3) void gemm128_kernel(
    const float* __restrict__ A, const float* __restrict__ A2,
    const int* __restrict__ rowmap,
    const float* __restrict__ W, const float* __restrict__ bias,
    float* __restrict__ out, int M, int relu)
{
    __shared__ float As[128][65];               // [k][m]
    __shared__ __align__(8) bf16 Ws[128][66];   // [n][k-half]
    const int tid = threadIdx.x;
    const int row0 = blockIdx.x * 64;
#pragma unroll
    for (int i = 0; i < 8; ++i) {
        int id = i * 256 + tid;
        int r = id >> 5;
        int c4 = (id & 31) << 2;
        float4 v = make_float4(0.f, 0.f, 0.f, 0.f);
        int gr = row0 + r;
        if (gr < M) {
            int ar = rowmap ? rowmap[gr] : gr;
            v = *(const float4*)&A[(size_t)ar * 128 + c4];
            if (A2) {
                float4 w = *(const float4*)&A2[(size_t)ar * 128 + c4];
                v.x += w.x; v.y += w.y; v.z += w.z; v.w += w.w;
            }
        }
        As[c4 + 0][r] = v.x; As[c4 + 1][r] = v.y; As[c4 + 2][r] = v.z; As[c4 + 3][r] = v.w;
    }
    const int m0 = (tid & 15) * 4;
    const int n0 = (tid >> 4) * 8;
    float acc[4][8];
#pragma unroll
    for (int i = 0; i < 4; ++i)
#pragma unroll
        for (int j = 0; j < 8; ++j) acc[i][j] = 0.f;

    for (int p = 0; p < 2; ++p) {
        if (p) __syncthreads();
#pragma unroll
        for (int i = 0; i < 8; ++i) {
            int id = i * 256 + tid;
            int n = id >> 4, koff = (id & 15) * 4;
            float4 w = *(const float4*)&W[(size_t)n * 128 + p * 64 + koff];
            *(uint32*)&Ws[n][koff]     = packbf(w.x, w.y);
            *(uint32*)&Ws[n][koff + 2] = packbf(w.z, w.w);
        }
        __syncthreads();
        for (int k2 = 0; k2 < 32; ++k2) {
            int kk = p * 64 + 2 * k2;
            float av0[4], av1[4];
#pragma unroll
            for (int i = 0; i < 4; ++i) { av0[i] = As[kk][m0 + i]; av1[i] = As[kk + 1][m0 + i]; }
#pragma unroll
            for (int j = 0; j < 8; ++j) {
                uint32 wp = *(const uint32*)&Ws[n0 + j][2 * k2];
                float w0 = bflo(wp), w1 = bfhi(wp);
#pragma unroll
                for (int i = 0; i < 4; ++i)
                    acc[i][j] = fmaf(av1[i], w1, fmaf(av0[i], w0, acc[i][j]));
            }
        }
    }
    float bv[8];
#pragma unroll
    for (int j = 0; j < 8; ++j) bv[j] = bias ? bias[n0 + j] : 0.f;
#pragma unroll
    for (int i = 0; i < 4; ++i) {
        int r = row0 + m0 + i;
        if (r < M) {
            float vv[8];
#pragma unroll
            for (int j = 0; j < 8; ++j) {
                float v = acc[i][j] + bv[j];
                vv[j] = relu ? fmaxf(v, 0.f) : v;
            }
            *(float4*)&out[(size_t)r * 128 + n0] = make_float4(vv[0], vv[1], vv[2], vv[3]);
            *(float4*)&out[(size_t)r * 128 + n0 + 4] = make_float4(vv[4], vv[5], vv[6], vv[7]);
        }
    }
}

// ---------------- CSR build: count -> scan -> fill ----------------
__global__ __launch_bounds__(256) void csr_count_kernel(
    const int* __restrict__ rel_rows, int* __restrict__ offs)
{
    int r = blockIdx.y;
    int e = blockIdx.x * 256 + threadIdx.x;
    int row = rel_rows[(size_t)r * NNZ_C + e];
    atomicAdd(&offs[(size_t)r * 70001 + row + 1], 1);
}

__global__ __launch_bounds__(1024) void scan_kernel(int* __restrict__ offs) {
    __shared__ int s[1024];
    int* a = offs + (size_t)blockIdx.x * 70001;
    const int tid = threadIdx.x;
    int carry = 0;
    for (int base = 0; base < 70001; base += 1024) {
        int i = base + tid;
        int x = (i < 70001) ? a[i] : 0;
        s[tid] = x;
        __syncthreads();
        for (int d = 1; d < 1024; d <<= 1) {
            int t = (tid >= d) ? s[tid - d] : 0;
            __syncthreads();
            s[tid] += t;
            __syncthreads();
        }
        if (i < 70001) a[i] = s[tid] + carry;
        carry += s[1023];
        __syncthreads();
    }
}

__global__ __launch_bounds__(256) void csr_fill_kernel(
    const int* __restrict__ rel_rows, const int* __restrict__ rel_cols,
    const float* __restrict__ rel_vals, const int* __restrict__ offs,
    int* __restrict__ cur, int* __restrict__ colv, unsigned short* __restrict__ valv)
{
    int r = blockIdx.y;
    int e = blockIdx.x * 256 + threadIdx.x;
    size_t rb = (size_t)r * NNZ_C;
    int row = rel_rows[rb + e];
    int slot = offs[(size_t)r * 70001 + row] + atomicAdd(&cur[(size_t)r * 70000 + row], 1);
    colv[rb + slot] = rel_cols[rb + e];
    valv[rb + slot] = __bfloat16_as_ushort(__float2bfloat16(rel_vals[rb + e]));
}

// ---------------- gather: t_r[row] = sum_e val * hab[col]  (wave per row) ----------------
__global__ __launch_bounds__(256) void gather_kernel(
    const uint32* __restrict__ hab, const int* __restrict__ colv,
    const unsigned short* __restrict__ valv, const int* __restrict__ offs,
    uint32* __restrict__ T)   // bf16 pairs, row stride 192 u32 (384 bf16)
{
    const int r = blockIdx.y;
    const int row = blockIdx.x * 4 + (threadIdx.x >> 6);
    const int lane = threadIdx.x & 63;
    const int* __restrict__ cv = colv + (size_t)r * NNZ_C;
    const unsigned short* __restrict__ vv = valv + (size_t)r * NNZ_C;
    const int* __restrict__ of = offs + (size_t)r * 70001;
    int e0 = of[row], e1 = of[row + 1];
    float ax = 0.f, ay = 0.f;
    int e = e0;
    for (; e + 2 <= e1; e += 2) {
        int c0 = cv[e], c1 = cv[e + 1];
        float v0 = __uint_as_float((uint32)vv[e] << 16);
        float v1 = __uint_as_float((uint32)vv[e + 1] << 16);
        uint32 u0 = hab[(size_t)c0 * 64 + lane];
        uint32 u1 = hab[(size_t)c1 * 64 + lane];
        ax += v0 * bflo(u0) + v1 * bflo(u1);
        ay += v0 * bfhi(u0) + v1 * bfhi(u1);
    }
    if (e < e1) {
        int c0 = cv[e];
        float v0 = __uint_as_float((uint32)vv[e] << 16);
        uint32 u0 = hab[(size_t)c0 * 64 + lane];
        ax += v0 * bflo(u0); ay += v0 * bfhi(u0);
    }
    T[(size_t)row * 192 + r * 64 + lane] = packbf(ax, ay);
}

// ---------------- weight prep: Wcat[seg][n][r*128+k] = bf16( (U @ W_r)[n][k] ) ----------
__global__ __launch_bounds__(256, 3) void wprep_kernel(
    const float* __restrict__ upi_w, const float* __restrict__ upu_w,
    const float* __restrict__ lin_r_w, int k, uint32* __restrict__ Wcat)
{
    __shared__ float As[128][65];
    __shared__ __align__(8) bf16 Ws[128][66];
    const int which = blockIdx.y, seg = which / 3, r = which % 3;
    const float* U  = (seg == 0 ? upi_w : upu_w) + (size_t)k * 16384;
    const float* Wr = lin_r_w + (size_t)(k * 3 + r) * 16384;
    uint32* out = Wcat + (size_t)seg * 32768;   // u32 row stride 256 (512 bf16)
    const int tid = threadIdx.x;
    const int row0 = blockIdx.x * 64;
#pragma unroll
    for (int i = 0; i < 8; ++i) {
        int id = i * 256 + tid;
        int rr = id >> 5, c4 = (id & 31) << 2;
        float4 v = *(const float4*)&U[(size_t)(row0 + rr) * 128 + c4];
        As[c4][rr] = v.x; As[c4+1][rr] = v.y; As[c4+2][rr] = v.z; As[c4+3][rr] = v.w;
    }
    const int m0 = (tid & 15) * 4;
    const int n0 = (tid >> 4) * 8;
    float acc[4][8];
#pragma unroll
    for (int i = 0; i < 4; ++i)
#pragma unroll
        for (int j = 0; j < 8; ++j) acc[i][j] = 0.f;
    for (int p = 0; p < 2; ++p) {
        if (p) __syncthreads();
        for (int i = 0; i < 32; ++i) {       // Ws[c][kf] = Wr[p*64+kf][c] (transposed)
            int id = i * 256 + tid;
            int c = id >> 6, kf = id & 63;
            Ws[c][kf] = __float2bfloat16(Wr[(size_t)(p * 64 + kf) * 128 + c]);
        }
        __syncthreads();
        for (int k2 = 0; k2 < 32; ++k2) {
            int kk = p * 64 + 2 * k2;
            float av0[4], av1[4];
#pragma unroll
            for (int i = 0; i < 4; ++i) { av0[i] = As[kk][m0 + i]; av1[i] = As[kk + 1][m0 + i]; }
#pragma unroll
            for (int j = 0; j < 8; ++j) {
                uint32 wp = *(const uint32*)&Ws[n0 + j][2 * k2];
                float w0 = bflo(wp), w1 = bfhi(wp);
#pragma unroll
                for (int i = 0; i < 4; ++i)
                    acc[i][j] = fmaf(av1[i], w1, fmaf(av0[i], w0, acc[i][j]));
            }
        }
    }
    // acc[i][j] = V[n = row0+m0+i][kk = n0+j]; write bf16 pairs at Wcat[n][r*128 + kk]
#pragma unroll
    for (int i = 0; i < 4; ++i) {
        int n = row0 + m0 + i;
#pragma unroll
        for (int j = 0; j < 8; j += 2)
            out[(size_t)n * 256 + (r * 128 + n0 + j) / 2] = packbf(acc[i][j], acc[i][j + 1]);
    }
}

// ---------------- U pack: Wcat[seg][n][384+j] = bf16(U[n][j]) ----------------
__global__ __launch_bounds__(256) void upack_kernel(
    const float* __restrict__ upi_w, const float* __restrict__ upu_w,
    int k, uint32* __restrict__ Wcat)
{
    int id = blockIdx.x * 256 + threadIdx.x;   // 16384 pairs
    int seg = id >> 13, p = id & 8191;
    int n = p >> 6, j2 = (p & 63);
    const float* U = (seg ? upu_w : upi_w) + (size_t)k * 16384;
    float2 w = *(const float2*)&U[(size_t)n * 128 + j2 * 2];
    Wcat[(size_t)seg * 32768 + (size_t)n * 256 + 192 + j2] = packbf(w.x, w.y);
}

// ---------------- HGNN update (MFMA, LDS-free): hab = relu([T|hab] @ Wcat^T + b) ----------
__global__ __launch_bounds__(256) void hgnn_update_mfma_kernel(
    const bf16* __restrict__ T,        // [70000][384] bf16
    uint32* __restrict__ hab,          // [70000][64] u32, read+write (in place)
    const bf16* __restrict__ Wcat,     // [128][512] bf16 (one segment)
    const float* __restrict__ bias, int row0, int M)
{
    const int tid = threadIdx.x;
    const int wv = tid >> 6, lane = tid & 63, quad = lane >> 4, lr = lane & 15;
    const int rbase = blockIdx.x * 64;
    const bf16* hb = (const bf16*)hab;
    f32x4 acc[4][2];
#pragma unroll
    for (int mt = 0; mt < 4; ++mt) { acc[mt][0] = (f32x4){0,0,0,0}; acc[mt][1] = (f32x4){0,0,0,0}; }
    int arow[4];
#pragma unroll
    for (int mt = 0; mt < 4; ++mt) {
        int rr = rbase + mt * 16 + lr;
        arow[mt] = row0 + (rr < M ? rr : M - 1);
    }
#pragma unroll
    for (int ks = 0; ks < 16; ++ks) {
        short8 b0 = *(const short8*)&Wcat[(size_t)(wv * 32 + lr) * 512 + ks * 32 + quad * 8];
        short8 b1 = *(const short8*)&Wcat[(size_t)(wv * 32 + 16 + lr) * 512 + ks * 32 + quad * 8];
#pragma unroll
        for (int mt = 0; mt < 4; ++mt) {
            short8 a;
            if (ks < 12) a = *(const short8*)&T[(size_t)arow[mt] * 384 + ks * 32 + quad * 8];
            else         a = *(const short8*)&hb[(size_t)arow[mt] * 128 + (ks - 12) * 32 + quad * 8];
            acc[mt][0] = __builtin_amdgcn_mfma_f32_16x16x32_bf16(a, b0, acc[mt][0], 0, 0, 0);
            acc[mt][1] = __builtin_amdgcn_mfma_f32_16x16x32_bf16(a, b1, acc[mt][1], 0, 0, 0);
        }
    }
    __syncthreads();   // barrier drains loads: all hab reads done before in-place writes
    unsigned short* hw = (unsigned short*)hab;
#pragma unroll
    for (int s = 0; s < 2; ++s) {
        int col = wv * 32 + s * 16 + lr;
        float bv = bias[col];
#pragma unroll
        for (int mt = 0; mt < 4; ++mt)
#pragma unroll
            for (int reg = 0; reg < 4; ++reg) {
                int rr = rbase + mt * 16 + quad * 4 + reg;
                if (rr < M) {
                    float v = fmaxf(acc[mt][s][reg] + bv, 0.f);
                    hw[(size_t)(row0 + rr) * 128 + col] = __bfloat16_as_ushort(__float2bfloat16(v));
                }
            }
    }
}

// ---------------- session prep ----------------
__global__ void session_prep_kernel(const int* __restrict__ ids, const int* __restrict__ uid,
                                    const float* __restrict__ u_type,
                                    int* __restrict__ lens, int* __restrict__ rowmap,
                                    float* __restrict__ out_target, float* __restrict__ out_utype)
{
    int n = blockIdx.x * 256 + threadIdx.x;
    if (n >= NSESS) return;
    int b = n & 255, s = n >> 8;
    const int* row = ids + (size_t)(b * 4 + s) * 50;
    int len = 0;
#pragma unroll
    for (int l = 0; l < 50; ++l) len += (row[l] != 0) ? 1 : 0;
    lens[n] = len;
    rowmap[n] = n * LP + (len - 2);
    out_target[n] = (float)row[len - 1];
    out_utype[n] = u_type[b];
}

// ---------------- c_hist gather from bf16 hab ----------------
__global__ void chist_kernel(const uint32* __restrict__ hab, const int* __restrict__ uid,
                             float* __restrict__ chist) {
    int n = blockIdx.x, d = threadIdx.x;
    uint32 u = hab[(size_t)(N_ITEMS_C + uid[n & 255]) * 64 + (d >> 1)];
    chist[(size_t)n * 128 + d] = (d & 1) ? bfhi(u) : bflo(u);
}

// ---------------- token embedding gather ----------------
__global__ void h0_gather_kernel(const float* __restrict__ id_emb, const int* __restrict__ ids,
                                 const int* __restrict__ lens, float* __restrict__ h0) {
    int g = blockIdx.x, d = threadIdx.x;
    int n = g / LP;
    int tt = g - n * LP;
    int len = lens[n];
    int b = n & 255, s = n >> 8;
    int id = (tt < len - 1) ? ids[(size_t)(b * 4 + s) * 50 + tt] : 0;
    h0[(size_t)g * 128 + d] = id_emb[(size_t)id * 128 + d];
}

// ---------------- GRU weight pack: f32 -> bf16 row-major ----------------
__global__ __launch_bounds__(256) void gru_wpack_kernel(
    const float* __restrict__ w_ih, const float* __restrict__ w_hh,
    uint32* __restrict__ wihb, uint32* __restrict__ whhb)
{
    int id = blockIdx.x * 256 + threadIdx.x;   // pair index, 73728 total
    if (id < 49152) {
        float2 w = *(const float2*)&w_ih[(size_t)id * 2];
        wihb[id] = packbf(w.x, w.y);
    } else {
        int j = id - 49152;                    // 24576 pairs
        float2 w = *(const float2*)&w_hh[(size_t)j * 2];
        whhb[j] = packbf(w.x, w.y);
    }
}

// ---------------- MFMA GRU: gi = m @ w_ih^T, gh = h @ w_hh^T, fused gates ----------------
__global__ __launch_bounds__(256, 2) void gru_mfma_kernel(
    const float* __restrict__ hEi, const float* __restrict__ hEo,
    float* __restrict__ h, const int* __restrict__ lens,
    const bf16* __restrict__ wihb,   // [384][256] bf16
    const bf16* __restrict__ whhb,   // [384][128] bf16
    const float* __restrict__ b_ih, const float* __restrict__ b_hh,
    const float* __restrict__ b_iah, const float* __restrict__ b_oah)
{
    __shared__ __align__(16) bf16 Agi[16][264];
    __shared__ __align__(16) bf16 Agh[16][136];
    const int tid = threadIdx.x;
    const int g0 = blockIdx.x * 16;

#pragma unroll
    for (int i = 0; i < 8; ++i) {
        int p = i * 256 + tid;
        int row = p >> 7, kp = p & 127;
        int g = g0 + row;
        int n = g / LP;
        int tt = g - n * LP;
        int len = lens[n];
        int kk = (kp & 63) * 2;
        float v0, v1;
        if (kp < 64) {
            v0 = b_iah[kk]; v1 = b_iah[kk + 1];
            if (tt >= 1 && tt < len - 1) {
                float2 e = *(const float2*)&hEi[(size_t)(g - 1) * 128 + kk];
                v0 += e.x; v1 += e.y;
            }
        } else {
            v0 = b_oah[kk]; v1 = b_oah[kk + 1];
            if (tt < len - 2) {
                float2 e = *(const float2*)&hEo[(size_t)(g + 1) * 128 + kk];
                v0 += e.x; v1 += e.y;
            }
        }
        *(uint32*)&Agi[row][kp * 2] = packbf(v0, v1);
    }
#pragma unroll
    for (int i = 0; i < 4; ++i) {
        int p = i * 256 + tid;
        int row = p >> 6, kp = p & 63;
        float2 e = *(const float2*)&h[(size_t)(g0 + row) * 128 + kp * 2];
        *(uint32*)&Agh[row][kp * 2] = packbf(e.x, e.y);
    }
    __syncthreads();

    const int wv = tid >> 6;
    const int lane = tid & 63;
    const int quad = lane >> 4;
    const int lr = lane & 15;
    const int c0 = wv * 32;

    f32x4 accI[2][3], accH[2][3];
#pragma unroll
    for (int s = 0; s < 2; ++s)
#pragma unroll
        for (int gte = 0; gte < 3; ++gte) {
            accI[s][gte] = (f32x4){0.f, 0.f, 0.f, 0.f};
            accH[s][gte] = (f32x4){0.f, 0.f, 0.f, 0.f};
        }

#pragma unroll
    for (int ks = 0; ks < 8; ++ks) {
        short8 a = *(const short8*)&Agi[lr][ks * 32 + quad * 8];
#pragma unroll
        for (int s = 0; s < 2; ++s)
#pragma unroll
            for (int gte = 0; gte < 3; ++gte) {
                int n0 = gte * 128 + c0 + s * 16 + lr;
                short8 b = *(const short8*)&wihb[(size_t)n0 * 256 + ks * 32 + quad * 8];
                accI[s][gte] = __builtin_amdgcn_mfma_f32_16x16x32_bf16(a, b, accI[s][gte], 0, 0, 0);
            }
    }
#pragma unroll
    for (int ks = 0; ks < 4; ++ks) {
        short8 a = *(const short8*)&Agh[lr][ks * 32 + quad * 8];
#pragma unroll
        for (int s = 0; s < 2; ++s)
#pragma unroll
            for (int gte = 0; gte < 3; ++gte) {
                int n0 = gte * 128 + c0 + s * 16 + lr;
                short8 b = *(const short8*)&whhb[(size_t)n0 * 128 + ks * 32 + quad * 8];
                accH[s][gte] = __builtin_amdgcn_mfma_f32_16x16x32_bf16(a, b, accH[s][gte], 0, 0, 0);
            }
    }

#pragma unroll
    for (int s = 0; s < 2; ++s) {
        int col = c0 + s * 16 + lr;
        float bir = b_ih[col], biz = b_ih[col + 128], bin = b_ih[col + 256];
        float bhr = b_hh[col], bhz = b_hh[col + 128], bhn = b_hh[col + 256];
#pragma unroll
        for (int reg = 0; reg < 4; ++reg) {
            int row = g0 + quad * 4 + reg;
            float gi_r = accI[s][0][reg] + bir, gh_r = accH[s][0][reg] + bhr;
            float gi_z = accI[s][1][reg] + biz, gh_z = accH[s][1][reg] + bhz;
            float gi_n = accI[s][2][reg] + bin, gh_n = accH[s][2][reg] + bhn;
            float rg = 1.f / (1.f + expf(-(gi_r + gh_r)));
            float zg = 1.f / (1.f + expf(-(gi_z + gh_z)));
            float ng = tanhf(gi_n + rg * gh_n);
            float ho = h[(size_t)row * 128 + col];
            h[(size_t)row * 128 + col] = ng + zg * (ho - ng);
        }
    }
}

// ---------------- attention readout + fuse layer -> reps (f32 out) ----------------
__global__ __launch_bounds__(128) void attn_fuse_kernel(
    const float* __restrict__ q1h, const float* __restrict__ q2h,
    const float* __restrict__ h, const float* __restrict__ chist,
    const int* __restrict__ lens, const float* __restrict__ att_w,
    const float* __restrict__ fuse_w, const float* __restrict__ fuse_b,
    float* __restrict__ out)
{
    __shared__ float q1s[128], aws[128], al[64], cv[256];
    const int n = blockIdx.x, tid = threadIdx.x;
    q1s[tid] = q1h[(size_t)n * 128 + tid];
    aws[tid] = att_w[tid];
    if (tid < 64) al[tid] = 0.f;
    __syncthreads();
    const int len = lens[n];
    if (tid < len - 1) {
        const float* q2 = &q2h[(size_t)(n * LP + tid) * 128];
        float s = 0.f;
        for (int d = 0; d < 128; ++d) {
            float x = q1s[d] + q2[d];
            s += aws[d] / (1.f + expf(-x));
        }
        al[tid] = s;
    }
    __syncthreads();
    float ssum = 0.f;
    for (int t = 0; t < len - 1; ++t) ssum += al[t];
    float inv = 1.f / (ssum + 1e-8f);
    float c = 0.f;
    for (int t = 0; t < len - 1; ++t)
        c += al[t] * inv * h[(size_t)(n * LP + t) * 128 + tid];
    cv[tid] = c;
    cv[128 + tid] = chist[(size_t)n * 128 + tid];
    __syncthreads();
    float s = fuse_b[tid];
    const float* fr = fuse_w + (size_t)tid * 256;
    for (int k = 0; k < 256; ++k) s += cv[k] * fr[k];
    out[(size_t)n * 128 + tid] = s;
}

// ============================================================================
extern "C" void kernel_launch(void* const* d_in, const int* in_sizes, int n_in,
                              void* d_out, int out_size, void* d_ws, size_t ws_size,
                              hipStream_t stream)
{
    const float* id_emb   = (const float*)d_in[0];
    const float* user_emb = (const float*)d_in[1];
    const float* lin_r_w  = (const float*)d_in[2];
    const float* upi_w    = (const float*)d_in[3];
    const float* upi_b    = (const float*)d_in[4];
    const float* upu_w    = (const float*)d_in[5];
    const float* upu_b    = (const float*)d_in[6];
    const float* w_ih     = (const float*)d_in[7];
    const float* w_hh     = (const float*)d_in[8];
    const float* b_ih     = (const float*)d_in[9];
    const float* b_hh     = (const float*)d_in[10];
    const float* b_iah    = (const float*)d_in[11];
    const float* b_oah    = (const float*)d_in[12];
    const float* ei_w     = (const float*)d_in[13];
    const float* ei_b     = (const float*)d_in[14];
    const float* eo_w     = (const float*)d_in[15];
    const float* eo_b     = (const float*)d_in[16];
    const float* q1_w     = (const float*)d_in[17];
    const float* q2_w     = (const float*)d_in[18];
    const float* att_w    = (const float*)d_in[19];
    const float* fuse_w   = (const float*)d_in[20];
    const float* fuse_b   = (const float*)d_in[21];
    const int*  rel_rows  = (const int*)d_in[22];
    const int*  rel_cols  = (const int*)d_in[23];
    const float* rel_vals = (const float*)d_in[24];
    const int*  ids       = (const int*)d_in[25];
    const int*  uid       = (const int*)d_in[26];
    const float* u_type   = (const float*)d_in[27];
    float* out = (float*)d_out;   // reps[131072] | target[1024] | u_type[1024]

    // ---- workspace layout (u32 units) ----
    uint32* W32  = (uint32*)d_ws;
    uint32* hab  = W32;                                   //  4,480,000 (bf16 nodes)
    uint32* T    = W32 + 4480000;                         // 13,440,000 (bf16, stride 192)
    int*   colv  = (int*)(W32 + 17920000);                //  2,400,000
    unsigned short* valv = (unsigned short*)(W32 + 20320000); // 2.4M ushort (1.2M u32)
    int*   offs  = (int*)(W32 + 21520000);                //  3 x 70001 (+pad)
    int*   cur   = (int*)(W32 + 21730004);                //  3 x 70000
    uint32* Wcat = W32 + 21940004;                        //  2 x 32768 (bf16 128x512 x2)
    // session overlays (live only after HGNN):
    float* sess_h  = (float*)(W32 + 4480000);             //  6,422,528 f  (in T region)
    float* sess_Ei = (float*)(W32 + 10902528);            //  6,422,528 f  (in T region)
    float* sess_Eo = (float*)(W32 + 17325056);            //  6,422,528 f  (over colv..Wcat)
    float* q2h     = sess_Ei;
    uint32* wihb   = W32;                                 //  49,152 (over dead hab)
    uint32* whhb   = W32 + 49152;                         //  24,576
    float* q1h   = (float*)(W32 + 23747584);              //  131,072
    float* chist = (float*)(W32 + 23878656);              //  131,072
    int*   lens  = (int*)(W32 + 24009728);                //  1024
    int*   rowmap= (int*)(W32 + 24010752);                //  1024  (end 24,011,776)
    if (ws_size < (size_t)27144192 * 4 + 4096) return;

    // ---- init + CSR build ----
    init_hab_kernel<<<17500, 256, 0, stream>>>((const float2*)id_emb, (const float2*)user_emb, hab);
    hipMemsetAsync(offs, 0, (size_t)(210004 + 210000) * 4, stream);
    csr_count_kernel<<<dim3(3125, 3), 256, 0, stream>>>(rel_rows, offs);
    scan_kernel<<<3, 1024, 0, stream>>>(offs);
    csr_fill_kernel<<<dim3(3125, 3), 256, 0, stream>>>(rel_rows, rel_cols, rel_vals,
                                                       offs, cur, colv, valv);

    // ---- HGNN: 2 layers, MFMA update, no atomics ----
    for (int k = 0; k < 2; ++k) {
        wprep_kernel<<<dim3(2, 6), 256, 0, stream>>>(upi_w, upu_w, lin_r_w, k, Wcat);
        upack_kernel<<<64, 256, 0, stream>>>(upi_w, upu_w, k, Wcat);
        gather_kernel<<<dim3(17500, 3), 256, 0, stream>>>(hab, colv, valv, offs, T);
        hgnn_update_mfma_kernel<<<782, 256, 0, stream>>>((const bf16*)T, hab,
            (const bf16*)Wcat, upi_b + k * 128, 0, N_ITEMS_C);
        hgnn_update_mfma_kernel<<<313, 256, 0, stream>>>((const bf16*)T, hab,
            (const bf16*)(Wcat + 32768), upu_b + k * 128, N_ITEMS_C, N_USERS_C);
    }

    // ---- session branch ----
    session_prep_kernel<<<4, 256, 0, stream>>>(ids, uid, u_type, lens, rowmap,
        out + 131072, out + 132096);
    chist_kernel<<<NSESS, 128, 0, stream>>>(hab, uid, chist);   // before overlays clobber hab/T
    h0_gather_kernel<<<NTOK, 128, 0, stream>>>(id_emb, ids, lens, sess_h);
    gemm128_kernel<<<784, 256, 0, stream>>>(sess_h, nullptr, nullptr, ei_w, ei_b, sess_Ei, NTOK, 0);
    gemm128_kernel<<<784, 256, 0, stream>>>(sess_h, nullptr, nullptr, eo_w, eo_b, sess_Eo, NTOK, 0);
    gru_wpack_kernel<<<288, 256, 0, stream>>>(w_ih, w_hh, wihb, whhb);   // hab dead now
    gru_mfma_kernel<<<NTOK / 16, 256, 0, stream>>>(sess_Ei, sess_Eo, sess_h, lens,
        (const bf16*)wihb, (const bf16*)whhb, b_ih, b_hh, b_iah, b_oah);
    gemm128_kernel<<<784, 256, 0, stream>>>(sess_h, nullptr, nullptr, q2_w, nullptr, q2h, NTOK, 0);
    gemm128_kernel<<<16, 256, 0, stream>>>(sess_h, nullptr, rowmap, q1_w, nullptr, q1h, NSESS, 0);
    attn_fuse_kernel<<<NSESS, 128, 0, stream>>>(q1h, q2h, sess_h, chist, lens,
        att_w, fuse_w, fuse_b, out);
}

// Round 8
// 1071.037 us; speedup vs baseline: 3.6021x; 1.2004x over previous
//
#include <hip/hip_runtime.h>
#include <hip/hip_bf16.h>

typedef __hip_bfloat16 bf16;
typedef unsigned int uint32;
typedef __attribute__((ext_vector_type(8))) short short8;   // 8 bf16 (4 VGPRs)
typedef __attribute__((ext_vector_type(4))) float f32x4;

#define N_ITEMS_C 50000
#define N_USERS_C 20000
#define N_NODES_C 70000
#define NNZ_C 800000
#define NSESS 1024
#define LP 49
#define NTOK (NSESS * LP)   // 50176

__device__ __forceinline__ float bflo(uint32 u) { return __uint_as_float(u << 16); }
__device__ __forceinline__ float bfhi(uint32 u) { return __uint_as_float(u & 0xffff0000u); }
__device__ __forceinline__ uint32 packbf(float a, float b) {
    return (uint32)__bfloat16_as_ushort(__float2bfloat16(a)) |
           ((uint32)__bfloat16_as_ushort(__float2bfloat16(b)) << 16);
}

// ---------------- init: hab = bf16(concat(id_emb, user_emb)) ----------------
__global__ void init_hab_kernel(const float2* __restrict__ idp, const float2* __restrict__ usp,
                                uint32* __restrict__ hab) {
    int i = blockIdx.x * 256 + threadIdx.x;           // pair index, 4,480,000 total
    float2 w = (i < 3200000) ? idp[i] : usp[i - 3200000];
    hab[i] = packbf(w.x, w.y);
}

// ---------------- CSR build: count -> scan -> fill ----------------
__global__ __launch_bounds__(256) void csr_count_kernel(
    const int* __restrict__ rel_rows, int* __restrict__ offs)
{
    int r = blockIdx.y;
    int e = blockIdx.x * 256 + threadIdx.x;
    int row = rel_rows[(size_t)r * NNZ_C + e];
    atomicAdd(&offs[(size_t)r * 70001 + row + 1], 1);
}

// shuffle-based scan: ~3 barriers per 1024-chunk (vs 20 for Hillis-Steele)
__global__ __launch_bounds__(1024) void scan_kernel(int* __restrict__ offs) {
    __shared__ int ws[16];
    __shared__ int carry_s;
    int* a = offs + (size_t)blockIdx.x * 70001;
    const int tid = threadIdx.x, lane = tid & 63, wid = tid >> 6;
    if (tid == 0) carry_s = 0;
    __syncthreads();
    for (int base = 0; base < 70001; base += 1024) {
        int i = base + tid;
        int x = (i < 70001) ? a[i] : 0;
#pragma unroll
        for (int d = 1; d < 64; d <<= 1) {
            int y = __shfl_up(x, d, 64);
            if (lane >= d) x += y;
        }
        if (lane == 63) ws[wid] = x;
        __syncthreads();
        if (wid == 0) {
            int w = (lane < 16) ? ws[lane] : 0;
#pragma unroll
            for (int d = 1; d < 16; d <<= 1) {
                int y = __shfl_up(w, d, 64);
                if (lane >= d) w += y;
            }
            if (lane < 16) ws[lane] = w;
        }
        __syncthreads();
        int prefix = carry_s + (wid > 0 ? ws[wid - 1] : 0);
        if (i < 70001) a[i] = x + prefix;
        __syncthreads();
        if (tid == 0) carry_s += ws[15];
        __syncthreads();
    }
}

// fill: ONE aligned 8B store per edge (col + bf16 val in high bits)
__global__ __launch_bounds__(256) void csr_fill_kernel(
    const int* __restrict__ rel_rows, const int* __restrict__ rel_cols,
    const float* __restrict__ rel_vals, const int* __restrict__ offs,
    int* __restrict__ cur, int2* __restrict__ edges)
{
    int r = blockIdx.y;
    int e = blockIdx.x * 256 + threadIdx.x;
    size_t rb = (size_t)r * NNZ_C;
    int row = rel_rows[rb + e];
    int slot = offs[(size_t)r * 70001 + row] + atomicAdd(&cur[(size_t)r * 70000 + row], 1);
    uint32 vb = (uint32)__bfloat16_as_ushort(__float2bfloat16(rel_vals[rb + e])) << 16;
    edges[rb + slot] = make_int2(rel_cols[rb + e], (int)vb);
}

// ---------------- gather: t_r[row] = sum_e val * hab[col]  (wave/row, 4-deep MLP) --------
__global__ __launch_bounds__(256) void gather_kernel(
    const uint32* __restrict__ hab, const int2* __restrict__ edges,
    const int* __restrict__ offs, uint32* __restrict__ T)
{
    const int r = blockIdx.y;
    const int row = blockIdx.x * 4 + (threadIdx.x >> 6);
    const int lane = threadIdx.x & 63;
    const int2* __restrict__ ed = edges + (size_t)r * NNZ_C;
    const int* __restrict__ of = offs + (size_t)r * 70001;
    int e0 = of[row], e1 = of[row + 1];
    float ax = 0.f, ay = 0.f;
    int e = e0;
    for (; e + 4 <= e1; e += 4) {
        int2 E0 = ed[e], E1 = ed[e + 1], E2 = ed[e + 2], E3 = ed[e + 3];
        uint32 u0 = hab[(size_t)E0.x * 64 + lane];
        uint32 u1 = hab[(size_t)E1.x * 64 + lane];
        uint32 u2 = hab[(size_t)E2.x * 64 + lane];
        uint32 u3 = hab[(size_t)E3.x * 64 + lane];
        float v0 = __uint_as_float((uint32)E0.y), v1 = __uint_as_float((uint32)E1.y);
        float v2 = __uint_as_float((uint32)E2.y), v3 = __uint_as_float((uint32)E3.y);
        ax += v0 * bflo(u0) + v1 * bflo(u1) + v2 * bflo(u2) + v3 * bflo(u3);
        ay += v0 * bfhi(u0) + v1 * bfhi(u1) + v2 * bfhi(u2) + v3 * bfhi(u3);
    }
    for (; e < e1; ++e) {
        int2 E = ed[e];
        uint32 u = hab[(size_t)E.x * 64 + lane];
        float v = __uint_as_float((uint32)E.y);
        ax += v * bflo(u); ay += v * bfhi(u);
    }
    T[(size_t)row * 192 + r * 64 + lane] = packbf(ax, ay);
}

// ---------------- weight prep: Wcat[seg][n][r*128+k] = bf16( (U @ W_r)[n][k] ) ----------
__global__ __launch_bounds__(256, 3) void wprep_kernel(
    const float* __restrict__ upi_w, const float* __restrict__ upu_w,
    const float* __restrict__ lin_r_w, int k, uint32* __restrict__ Wcat)
{
    __shared__ float As[128][65];
    __shared__ __align__(8) bf16 Ws[128][66];
    const int which = blockIdx.y, seg = which / 3, r = which % 3;
    const float* U  = (seg == 0 ? upi_w : upu_w) + (size_t)k * 16384;
    const float* Wr = lin_r_w + (size_t)(k * 3 + r) * 16384;
    uint32* out = Wcat + (size_t)seg * 32768;   // u32 row stride 256 (512 bf16)
    const int tid = threadIdx.x;
    const int row0 = blockIdx.x * 64;
#pragma unroll
    for (int i = 0; i < 8; ++i) {
        int id = i * 256 + tid;
        int rr = id >> 5, c4 = (id & 31) << 2;
        float4 v = *(const float4*)&U[(size_t)(row0 + rr) * 128 + c4];
        As[c4][rr] = v.x; As[c4+1][rr] = v.y; As[c4+2][rr] = v.z; As[c4+3][rr] = v.w;
    }
    const int m0 = (tid & 15) * 4;
    const int n0 = (tid >> 4) * 8;
    float acc[4][8];
#pragma unroll
    for (int i = 0; i < 4; ++i)
#pragma unroll
        for (int j = 0; j < 8; ++j) acc[i][j] = 0.f;
    for (int p = 0; p < 2; ++p) {
        if (p) __syncthreads();
        for (int i = 0; i < 32; ++i) {       // Ws[c][kf] = Wr[p*64+kf][c] (transposed)
            int id = i * 256 + tid;
            int c = id >> 6, kf = id & 63;
            Ws[c][kf] = __float2bfloat16(Wr[(size_t)(p * 64 + kf) * 128 + c]);
        }
        __syncthreads();
        for (int k2 = 0; k2 < 32; ++k2) {
            int kk = p * 64 + 2 * k2;
            float av0[4], av1[4];
#pragma unroll
            for (int i = 0; i < 4; ++i) { av0[i] = As[kk][m0 + i]; av1[i] = As[kk + 1][m0 + i]; }
#pragma unroll
            for (int j = 0; j < 8; ++j) {
                uint32 wp = *(const uint32*)&Ws[n0 + j][2 * k2];
                float w0 = bflo(wp), w1 = bfhi(wp);
#pragma unroll
                for (int i = 0; i < 4; ++i)
                    acc[i][j] = fmaf(av1[i], w1, fmaf(av0[i], w0, acc[i][j]));
            }
        }
    }
#pragma unroll
    for (int i = 0; i < 4; ++i) {
        int n = row0 + m0 + i;
#pragma unroll
        for (int j = 0; j < 8; j += 2)
            out[(size_t)n * 256 + (r * 128 + n0 + j) / 2] = packbf(acc[i][j], acc[i][j + 1]);
    }
}

// ---------------- U pack: Wcat[seg][n][384+j] = bf16(U[n][j]) ----------------
__global__ __launch_bounds__(256) void upack_kernel(
    const float* __restrict__ upi_w, const float* __restrict__ upu_w,
    int k, uint32* __restrict__ Wcat)
{
    int id = blockIdx.x * 256 + threadIdx.x;   // 16384 pairs
    int seg = id >> 13, p = id & 8191;
    int n = p >> 6, j2 = (p & 63);
    const float* U = (seg ? upu_w : upi_w) + (size_t)k * 16384;
    float2 w = *(const float2*)&U[(size_t)n * 128 + j2 * 2];
    Wcat[(size_t)seg * 32768 + (size_t)n * 256 + 192 + j2] = packbf(w.x, w.y);
}

// ---------------- HGNN update (MFMA, LDS-free): hab = relu([T|hab] @ Wcat^T + b) ----------
__global__ __launch_bounds__(256) void hgnn_update_mfma_kernel(
    const bf16* __restrict__ T, uint32* __restrict__ hab,
    const bf16* __restrict__ Wcat, const float* __restrict__ bias, int row0, int M)
{
    const int tid = threadIdx.x;
    const int wv = tid >> 6, lane = tid & 63, quad = lane >> 4, lr = lane & 15;
    const int rbase = blockIdx.x * 64;
    const bf16* hb = (const bf16*)hab;
    f32x4 acc[4][2];
#pragma unroll
    for (int mt = 0; mt < 4; ++mt) { acc[mt][0] = (f32x4){0,0,0,0}; acc[mt][1] = (f32x4){0,0,0,0}; }
    int arow[4];
#pragma unroll
    for (int mt = 0; mt < 4; ++mt) {
        int rr = rbase + mt * 16 + lr;
        arow[mt] = row0 + (rr < M ? rr : M - 1);
    }
#pragma unroll
    for (int ks = 0; ks < 16; ++ks) {
        short8 b0 = *(const short8*)&Wcat[(size_t)(wv * 32 + lr) * 512 + ks * 32 + quad * 8];
        short8 b1 = *(const short8*)&Wcat[(size_t)(wv * 32 + 16 + lr) * 512 + ks * 32 + quad * 8];
#pragma unroll
        for (int mt = 0; mt < 4; ++mt) {
            short8 a;
            if (ks < 12) a = *(const short8*)&T[(size_t)arow[mt] * 384 + ks * 32 + quad * 8];
            else         a = *(const short8*)&hb[(size_t)arow[mt] * 128 + (ks - 12) * 32 + quad * 8];
            acc[mt][0] = __builtin_amdgcn_mfma_f32_16x16x32_bf16(a, b0, acc[mt][0], 0, 0, 0);
            acc[mt][1] = __builtin_amdgcn_mfma_f32_16x16x32_bf16(a, b1, acc[mt][1], 0, 0, 0);
        }
    }
    __syncthreads();   // drain loads: all hab reads done before in-place writes
    unsigned short* hw = (unsigned short*)hab;
#pragma unroll
    for (int s = 0; s < 2; ++s) {
        int col = wv * 32 + s * 16 + lr;
        float bv = bias[col];
#pragma unroll
        for (int mt = 0; mt < 4; ++mt)
#pragma unroll
            for (int reg = 0; reg < 4; ++reg) {
                int rr = rbase + mt * 16 + quad * 4 + reg;
                if (rr < M) {
                    float v = fmaxf(acc[mt][s][reg] + bv, 0.f);
                    hw[(size_t)(row0 + rr) * 128 + col] = __bfloat16_as_ushort(__float2bfloat16(v));
                }
            }
    }
}

// ---------------- generic MFMA NT gemm (LDS-free, bf16 A/W, 1-2 outputs) ----------------
// O[M,128] = A[M,128] @ W^T (+bias). Optional rowmap on A rows.
__global__ __launch_bounds__(256) void mfma_nt_kernel(
    const bf16* __restrict__ A, const int* __restrict__ rowmap,
    const bf16* __restrict__ W0, const bf16* __restrict__ W1,
    const float* __restrict__ b0, const float* __restrict__ b1,
    float* __restrict__ O0, float* __restrict__ O1, int M)
{
    const int tid = threadIdx.x;
    const int wv = tid >> 6, lane = tid & 63, quad = lane >> 4, lr = lane & 15;
    const int rbase = blockIdx.x * 64;
    int arow[4];
#pragma unroll
    for (int mt = 0; mt < 4; ++mt) {
        int rr = rbase + mt * 16 + lr;
        rr = rr < M ? rr : M - 1;
        arow[mt] = rowmap ? rowmap[rr] : rr;
    }
    f32x4 acc0[4][2], acc1[4][2];
#pragma unroll
    for (int mt = 0; mt < 4; ++mt) {
        acc0[mt][0] = (f32x4){0,0,0,0}; acc0[mt][1] = (f32x4){0,0,0,0};
        acc1[mt][0] = (f32x4){0,0,0,0}; acc1[mt][1] = (f32x4){0,0,0,0};
    }
#pragma unroll
    for (int ks = 0; ks < 4; ++ks) {
        short8 b00 = *(const short8*)&W0[(size_t)(wv * 32 + lr) * 128 + ks * 32 + quad * 8];
        short8 b01 = *(const short8*)&W0[(size_t)(wv * 32 + 16 + lr) * 128 + ks * 32 + quad * 8];
        short8 b10, b11;
        if (W1) {
            b10 = *(const short8*)&W1[(size_t)(wv * 32 + lr) * 128 + ks * 32 + quad * 8];
            b11 = *(const short8*)&W1[(size_t)(wv * 32 + 16 + lr) * 128 + ks * 32 + quad * 8];
        }
#pragma unroll
        for (int mt = 0; mt < 4; ++mt) {
            short8 a = *(const short8*)&A[(size_t)arow[mt] * 128 + ks * 32 + quad * 8];
            acc0[mt][0] = __builtin_amdgcn_mfma_f32_16x16x32_bf16(a, b00, acc0[mt][0], 0, 0, 0);
            acc0[mt][1] = __builtin_amdgcn_mfma_f32_16x16x32_bf16(a, b01, acc0[mt][1], 0, 0, 0);
            if (W1) {
                acc1[mt][0] = __builtin_amdgcn_mfma_f32_16x16x32_bf16(a, b10, acc1[mt][0], 0, 0, 0);
                acc1[mt][1] = __builtin_amdgcn_mfma_f32_16x16x32_bf16(a, b11, acc1[mt][1], 0, 0, 0);
            }
        }
    }
#pragma unroll
    for (int s = 0; s < 2; ++s) {
        int col = wv * 32 + s * 16 + lr;
        float bv0 = b0 ? b0[col] : 0.f;
        float bv1 = (W1 && b1) ? b1[col] : 0.f;
#pragma unroll
        for (int mt = 0; mt < 4; ++mt)
#pragma unroll
            for (int reg = 0; reg < 4; ++reg) {
                int rr = rbase + mt * 16 + quad * 4 + reg;
                if (rr < M) {
                    O0[(size_t)rr * 128 + col] = acc0[mt][s][reg] + bv0;
                    if (W1) O1[(size_t)rr * 128 + col] = acc1[mt][s][reg] + bv1;
                }
            }
    }
}

// ---------------- session prep ----------------
__global__ void session_prep_kernel(const int* __restrict__ ids, const int* __restrict__ uid,
                                    const float* __restrict__ u_type,
                                    int* __restrict__ lens, int* __restrict__ rowmap,
                                    float* __restrict__ out_target, float* __restrict__ out_utype)
{
    int n = blockIdx.x * 256 + threadIdx.x;
    if (n >= NSESS) return;
    int b = n & 255, s = n >> 8;
    const int* row = ids + (size_t)(b * 4 + s) * 50;
    int len = 0;
#pragma unroll
    for (int l = 0; l < 50; ++l) len += (row[l] != 0) ? 1 : 0;
    lens[n] = len;
    rowmap[n] = n * LP + (len - 2);
    out_target[n] = (float)row[len - 1];
    out_utype[n] = u_type[b];
}

// ---------------- c_hist gather from bf16 hab ----------------
__global__ void chist_kernel(const uint32* __restrict__ hab, const int* __restrict__ uid,
                             float* __restrict__ chist) {
    int n = blockIdx.x, d = threadIdx.x;
    uint32 u = hab[(size_t)(N_ITEMS_C + uid[n & 255]) * 64 + (d >> 1)];
    chist[(size_t)n * 128 + d] = (d & 1) ? bfhi(u) : bflo(u);
}

// ---------------- token embedding gather -> bf16 h ----------------
__global__ void h0_gather_kernel(const float* __restrict__ id_emb, const int* __restrict__ ids,
                                 const int* __restrict__ lens, uint32* __restrict__ hb) {
    int g = blockIdx.x, d = threadIdx.x;   // 64 threads, d = pair index
    int n = g / LP;
    int tt = g - n * LP;
    int len = lens[n];
    int b = n & 255, s = n >> 8;
    int id = (tt < len - 1) ? ids[(size_t)(b * 4 + s) * 50 + tt] : 0;
    float2 e = *(const float2*)&id_emb[(size_t)id * 128 + d * 2];
    hb[(size_t)g * 64 + d] = packbf(e.x, e.y);
}

// ---------------- pack all session weights f32 -> bf16 ----------------
__global__ __launch_bounds__(256) void epack_kernel(
    const float* __restrict__ w_ih, const float* __restrict__ w_hh,
    const float* __restrict__ ei_w, const float* __restrict__ eo_w,
    const float* __restrict__ q2_w, const float* __restrict__ q1_w,
    uint32* __restrict__ dst)
{
    int id = blockIdx.x * 256 + threadIdx.x;   // 106,496 pairs total
    const float* src; int off;
    if      (id <  49152) { src = w_ih; off = id; }
    else if (id <  73728) { src = w_hh; off = id - 49152; }
    else if (id <  81920) { src = ei_w; off = id - 73728; }
    else if (id <  90112) { src = eo_w; off = id - 81920; }
    else if (id <  98304) { src = q2_w; off = id - 90112; }
    else                  { src = q1_w; off = id - 98304; }
    float2 w = *(const float2*)&src[(size_t)off * 2];
    dst[id] = packbf(w.x, w.y);
}

// ---------------- MFMA GRU over bf16 h (in-place) ----------------
__global__ __launch_bounds__(256, 2) void gru_mfma_kernel(
    const float* __restrict__ hEi, const float* __restrict__ hEo,
    uint32* __restrict__ hb, const int* __restrict__ lens,
    const bf16* __restrict__ wihb,   // [384][256] bf16
    const bf16* __restrict__ whhb,   // [384][128] bf16
    const float* __restrict__ b_ih, const float* __restrict__ b_hh,
    const float* __restrict__ b_iah, const float* __restrict__ b_oah)
{
    __shared__ __align__(16) bf16 Agi[16][264];
    __shared__ __align__(16) bf16 Agh[16][136];
    const int tid = threadIdx.x;
    const int g0 = blockIdx.x * 16;

#pragma unroll
    for (int i = 0; i < 8; ++i) {
        int p = i * 256 + tid;
        int row = p >> 7, kp = p & 127;
        int g = g0 + row;
        int n = g / LP;
        int tt = g - n * LP;
        int len = lens[n];
        int kk = (kp & 63) * 2;
        float v0, v1;
        if (kp < 64) {
            v0 = b_iah[kk]; v1 = b_iah[kk + 1];
            if (tt >= 1 && tt < len - 1) {
                float2 e = *(const float2*)&hEi[(size_t)(g - 1) * 128 + kk];
                v0 += e.x; v1 += e.y;
            }
        } else {
            v0 = b_oah[kk]; v1 = b_oah[kk + 1];
            if (tt < len - 2) {
                float2 e = *(const float2*)&hEo[(size_t)(g + 1) * 128 + kk];
                v0 += e.x; v1 += e.y;
            }
        }
        *(uint32*)&Agi[row][kp * 2] = packbf(v0, v1);
    }
#pragma unroll
    for (int i = 0; i < 4; ++i) {
        int p = i * 256 + tid;
        int row = p >> 6, kp = p & 63;
        *(uint32*)&Agh[row][kp * 2] = hb[(size_t)(g0 + row) * 64 + kp];
    }
    __syncthreads();

    const int wv = tid >> 6;
    const int lane = tid & 63;
    const int quad = lane >> 4;
    const int lr = lane & 15;
    const int c0 = wv * 32;

    f32x4 accI[2][3], accH[2][3];
#pragma unroll
    for (int s = 0; s < 2; ++s)
#pragma unroll
        for (int gte = 0; gte < 3; ++gte) {
            accI[s][gte] = (f32x4){0.f, 0.f, 0.f, 0.f};
            accH[s][gte] = (f32x4){0.f, 0.f, 0.f, 0.f};
        }

#pragma unroll
    for (int ks = 0; ks < 8; ++ks) {
        short8 a = *(const short8*)&Agi[lr][ks * 32 + quad * 8];
#pragma unroll
        for (int s = 0; s < 2; ++s)
#pragma unroll
            for (int gte = 0; gte < 3; ++gte) {
                int n0 = gte * 128 + c0 + s * 16 + lr;
                short8 b = *(const short8*)&wihb[(size_t)n0 * 256 + ks * 32 + quad * 8];
                accI[s][gte] = __builtin_amdgcn_mfma_f32_16x16x32_bf16(a, b, accI[s][gte], 0, 0, 0);
            }
    }
#pragma unroll
    for (int ks = 0; ks < 4; ++ks) {
        short8 a = *(const short8*)&Agh[lr][ks * 32 + quad * 8];
#pragma unroll
        for (int s = 0; s < 2; ++s)
#pragma unroll
            for (int gte = 0; gte < 3; ++gte) {
                int n0 = gte * 128 + c0 + s * 16 + lr;
                short8 b = *(const short8*)&whhb[(size_t)n0 * 128 + ks * 32 + quad * 8];
                accH[s][gte] = __builtin_amdgcn_mfma_f32_16x16x32_bf16(a, b, accH[s][gte], 0, 0, 0);
            }
    }

    unsigned short* hu = (unsigned short*)hb;
#pragma unroll
    for (int s = 0; s < 2; ++s) {
        int col = c0 + s * 16 + lr;
        float bir = b_ih[col], biz = b_ih[col + 128], bin = b_ih[col + 256];
        float bhr = b_hh[col], bhz = b_hh[col + 128], bhn = b_hh[col + 256];
#pragma unroll
        for (int reg = 0; reg < 4; ++reg) {
            int row = g0 + quad * 4 + reg;
            float gi_r = accI[s][0][reg] + bir, gh_r = accH[s][0][reg] + bhr;
            float gi_z = accI[s][1][reg] + biz, gh_z = accH[s][1][reg] + bhz;
            float gi_n = accI[s][2][reg] + bin, gh_n = accH[s][2][reg] + bhn;
            float rg = 1.f / (1.f + expf(-(gi_r + gh_r)));
            float zg = 1.f / (1.f + expf(-(gi_z + gh_z)));
            float ng = tanhf(gi_n + rg * gh_n);
            size_t idx = (size_t)row * 128 + col;
            float ho = __uint_as_float((uint32)hu[idx] << 16);
            hu[idx] = __bfloat16_as_ushort(__float2bfloat16(ng + zg * (ho - ng)));
        }
    }
}

// ---------------- attention readout + fuse layer -> reps (f32 out) ----------------
__global__ __launch_bounds__(128) void attn_fuse_kernel(
    const float* __restrict__ q1h, const float* __restrict__ q2h,
    const unsigned short* __restrict__ hu, const float* __restrict__ chist,
    const int* __restrict__ lens, const float* __restrict__ att_w,
    const float* __restrict__ fuse_w, const float* __restrict__ fuse_b,
    float* __restrict__ out)
{
    __shared__ float q1s[128], aws[128], al[64], cv[256];
    const int n = blockIdx.x, tid = threadIdx.x;
    q1s[tid] = q1h[(size_t)n * 128 + tid];
    aws[tid] = att_w[tid];
    if (tid < 64) al[tid] = 0.f;
    __syncthreads();
    const int len = lens[n];
    if (tid < len - 1) {
        const float* q2 = &q2h[(size_t)(n * LP + tid) * 128];
        float s = 0.f;
        for (int d = 0; d < 128; ++d) {
            float x = q1s[d] + q2[d];
            s += aws[d] / (1.f + expf(-x));
        }
        al[tid] = s;
    }
    __syncthreads();
    float ssum = 0.f;
    for (int t = 0; t < len - 1; ++t) ssum += al[t];
    float inv = 1.f / (ssum + 1e-8f);
    float c = 0.f;
    for (int t = 0; t < len - 1; ++t) {
        float hv = __uint_as_float((uint32)hu[(size_t)(n * LP + t) * 128 + tid] << 16);
        c += al[t] * inv * hv;
    }
    cv[tid] = c;
    cv[128 + tid] = chist[(size_t)n * 128 + tid];
    __syncthreads();
    float s = fuse_b[tid];
    const float* fr = fuse_w + (size_t)tid * 256;
    for (int k = 0; k < 256; ++k) s += cv[k] * fr[k];
    out[(size_t)n * 128 + tid] = s;
}

// ============================================================================
extern "C" void kernel_launch(void* const* d_in, const int* in_sizes, int n_in,
                              void* d_out, int out_size, void* d_ws, size_t ws_size,
                              hipStream_t stream)
{
    const float* id_emb   = (const float*)d_in[0];
    const float* user_emb = (const float*)d_in[1];
    const float* lin_r_w  = (const float*)d_in[2];
    const float* upi_w    = (const float*)d_in[3];
    const float* upi_b    = (const float*)d_in[4];
    const float* upu_w    = (const float*)d_in[5];
    const float* upu_b    = (const float*)d_in[6];
    const float* w_ih     = (const float*)d_in[7];
    const float* w_hh     = (const float*)d_in[8];
    const float* b_ih     = (const float*)d_in[9];
    const float* b_hh     = (const float*)d_in[10];
    const float* b_iah    = (const float*)d_in[11];
    const float* b_oah    = (const float*)d_in[12];
    const float* ei_w     = (const float*)d_in[13];
    const float* ei_b     = (const float*)d_in[14];
    const float* eo_w     = (const float*)d_in[15];
    const float* eo_b     = (const float*)d_in[16];
    const float* q1_w     = (const float*)d_in[17];
    const float* q2_w     = (const float*)d_in[18];
    const float* att_w    = (const float*)d_in[19];
    const float* fuse_w   = (const float*)d_in[20];
    const float* fuse_b   = (const float*)d_in[21];
    const int*  rel_rows  = (const int*)d_in[22];
    const int*  rel_cols  = (const int*)d_in[23];
    const float* rel_vals = (const float*)d_in[24];
    const int*  ids       = (const int*)d_in[25];
    const int*  uid       = (const int*)d_in[26];
    const float* u_type   = (const float*)d_in[27];
    float* out = (float*)d_out;   // reps[131072] | target[1024] | u_type[1024]

    // ---- workspace layout (u32 units) ----
    uint32* W32   = (uint32*)d_ws;
    uint32* hab   = W32;                                  //  4,480,000 (bf16 nodes)
    uint32* T     = W32 + 4480000;                        // 13,440,000 (bf16, stride 192)
    int2*   edges = (int2*)(W32 + 17920000);              //  2,400,000 int2 (4.8M u32)
    int*    offs  = (int*)(W32 + 22720000);               //  3 x 70001 (+pad to 210,004)
    int*    cur   = (int*)(W32 + 22930004);               //  3 x 70000
    uint32* Wcat  = W32 + 23140004;                       //  2 x 32768
    float*  q1h   = (float*)(W32 + 23205540);             //  131,072
    float*  chist = (float*)(W32 + 23336612);             //  131,072
    int*    lens  = (int*)(W32 + 23467684);               //  1024
    int*    rowmap= (int*)(W32 + 23468708);               //  1024   (end 23,469,732)
    // session overlays (live only after HGNN):
    uint32* sess_hb = W32;                                // 3,211,264 u32 (bf16 h, over hab)
    float* sess_Ei  = (float*)(W32 + 4480000);            // 6,422,528 f (in T region)
    float* sess_Eo  = (float*)(W32 + 10902528);           // 6,422,528 f (in T region)
    float* q2h      = sess_Ei;                            // Ei dead after GRU
    uint32* wpk     = W32 + 17920000;                     // packed session wts (over edges)
    uint32* wihb = wpk;              // 49,152
    uint32* whhb = wpk + 49152;      // 24,576
    uint32* eiwb = wpk + 73728;      //  8,192
    uint32* eowb = wpk + 81920;      //  8,192
    uint32* q2wb = wpk + 90112;      //  8,192
    uint32* q1wb = wpk + 98304;      //  8,192
    if (ws_size < (size_t)27144192 * 4 + 4096) return;

    // ---- init + CSR build ----
    init_hab_kernel<<<17500, 256, 0, stream>>>((const float2*)id_emb, (const float2*)user_emb, hab);
    hipMemsetAsync(offs, 0, (size_t)(210004 + 210000) * 4, stream);
    csr_count_kernel<<<dim3(3125, 3), 256, 0, stream>>>(rel_rows, offs);
    scan_kernel<<<3, 1024, 0, stream>>>(offs);
    csr_fill_kernel<<<dim3(3125, 3), 256, 0, stream>>>(rel_rows, rel_cols, rel_vals,
                                                       offs, cur, edges);

    // ---- HGNN: 2 layers, MFMA update, no atomics ----
    for (int k = 0; k < 2; ++k) {
        wprep_kernel<<<dim3(2, 6), 256, 0, stream>>>(upi_w, upu_w, lin_r_w, k, Wcat);
        upack_kernel<<<64, 256, 0, stream>>>(upi_w, upu_w, k, Wcat);
        gather_kernel<<<dim3(17500, 3), 256, 0, stream>>>(hab, edges, offs, T);
        hgnn_update_mfma_kernel<<<782, 256, 0, stream>>>((const bf16*)T, hab,
            (const bf16*)Wcat, upi_b + k * 128, 0, N_ITEMS_C);
        hgnn_update_mfma_kernel<<<313, 256, 0, stream>>>((const bf16*)T, hab,
            (const bf16*)(Wcat + 32768), upu_b + k * 128, N_ITEMS_C, N_USERS_C);
    }

    // ---- session branch ----
    session_prep_kernel<<<4, 256, 0, stream>>>(ids, uid, u_type, lens, rowmap,
        out + 131072, out + 132096);
    chist_kernel<<<NSESS, 128, 0, stream>>>(hab, uid, chist);   // before sess_hb overwrites hab
    epack_kernel<<<416, 256, 0, stream>>>(w_ih, w_hh, ei_w, eo_w, q2_w, q1_w, wpk);
    h0_gather_kernel<<<NTOK, 64, 0, stream>>>(id_emb, ids, lens, sess_hb);
    mfma_nt_kernel<<<784, 256, 0, stream>>>((const bf16*)sess_hb, nullptr,
        (const bf16*)eiwb, (const bf16*)eowb, ei_b, eo_b, sess_Ei, sess_Eo, NTOK);
    gru_mfma_kernel<<<NTOK / 16, 256, 0, stream>>>(sess_Ei, sess_Eo, sess_hb, lens,
        (const bf16*)wihb, (const bf16*)whhb, b_ih, b_hh, b_iah, b_oah);
    mfma_nt_kernel<<<784, 256, 0, stream>>>((const bf16*)sess_hb, nullptr,
        (const bf16*)q2wb, nullptr, nullptr, nullptr, q2h, nullptr, NTOK);
    mfma_nt_kernel<<<16, 256, 0, stream>>>((const bf16*)sess_hb, rowmap,
        (const bf16*)q1wb, nullptr, nullptr, nullptr, q1h, nullptr, NSESS);
    attn_fuse_kernel<<<NSESS, 128, 0, stream>>>(q1h, q2h, (const unsigned short*)sess_hb,
        chist, lens, att_w, fuse_w, fuse_b, out);
}

// Round 9
// 872.681 us; speedup vs baseline: 4.4209x; 1.2273x over previous
//
#include <hip/hip_runtime.h>
#include <hip/hip_bf16.h>

typedef __hip_bfloat16 bf16;
typedef unsigned int uint32;
typedef __attribute__((ext_vector_type(8))) short short8;   // 8 bf16 (4 VGPRs)
typedef __attribute__((ext_vector_type(4))) float f32x4;

#define N_ITEMS_C 50000
#define N_USERS_C 20000
#define N_NODES_C 70000
#define NNZ_C 800000
#define NSESS 1024
#define LP 49
#define NTOK (NSESS * LP)   // 50176
#define NBK 137             // coarse buckets: row >> 9

__device__ __forceinline__ float bflo(uint32 u) { return __uint_as_float(u << 16); }
__device__ __forceinline__ float bfhi(uint32 u) { return __uint_as_float(u & 0xffff0000u); }
__device__ __forceinline__ uint32 packbf(float a, float b) {
    return (uint32)__bfloat16_as_ushort(__float2bfloat16(a)) |
           ((uint32)__bfloat16_as_ushort(__float2bfloat16(b)) << 16);
}

// ---------------- init: hab = bf16(concat(id_emb, user_emb)) ----------------
__global__ void init_hab_kernel(const float2* __restrict__ idp, const float2* __restrict__ usp,
                                uint32* __restrict__ hab) {
    int i = blockIdx.x * 256 + threadIdx.x;           // pair index, 4,480,000 total
    float2 w = (i < 3200000) ? idp[i] : usp[i - 3200000];
    hab[i] = packbf(w.x, w.y);
}

// ================= CSR build: coarse-bucket sort with coalesced writes =================
// A1: per-block LDS hist over 137 buckets -> global bhist
__global__ __launch_bounds__(256) void bucket_hist_kernel(
    const int* __restrict__ rel_rows, int* __restrict__ bhist)
{
    __shared__ int hist[NBK];
    const int r = blockIdx.y, tid = threadIdx.x;
    if (tid < NBK) hist[tid] = 0;
    __syncthreads();
    const int* rr = rel_rows + (size_t)r * NNZ_C;
#pragma unroll
    for (int i = 0; i < 16; ++i) {
        int e = blockIdx.x * 4096 + i * 256 + tid;
        if (e < NNZ_C) atomicAdd(&hist[rr[e] >> 9], 1);
    }
    __syncthreads();
    if (tid < NBK && hist[tid]) atomicAdd(&bhist[r * NBK + tid], hist[tid]);
}

// A2: scan bucket totals -> bbase[r][0..NBK]
__global__ __launch_bounds__(256) void bucket_scan_kernel(
    const int* __restrict__ bhist, int* __restrict__ bbase)
{
    __shared__ int s[256];
    const int tid = threadIdx.x;
    for (int r = 0; r < 3; ++r) {
        s[tid] = (tid < NBK) ? bhist[r * NBK + tid] : 0;
        __syncthreads();
        for (int d = 1; d < 256; d <<= 1) {
            int t = (tid >= d) ? s[tid - d] : 0;
            __syncthreads();
            s[tid] += t;
            __syncthreads();
        }
        if (tid < NBK) bbase[r * (NBK + 1) + tid + 1] = s[tid];
        if (tid == 0) bbase[r * (NBK + 1)] = 0;
        __syncthreads();
    }
}

// A3: scatter edges into bucket-contiguous tmp (int2: packed(col|v15), row)
__global__ __launch_bounds__(256) void bucket_scatter_kernel(
    const int* __restrict__ rel_rows, const int* __restrict__ rel_cols,
    const float* __restrict__ rel_vals, const int* __restrict__ bbase,
    int* __restrict__ cursor, int2* __restrict__ tmp)
{
    __shared__ int hist[NBK], gbase[NBK], cur2[NBK];
    const int r = blockIdx.y, tid = threadIdx.x;
    if (tid < NBK) { hist[tid] = 0; cur2[tid] = 0; }
    __syncthreads();
    const int* rr = rel_rows + (size_t)r * NNZ_C;
    const int* rc = rel_cols + (size_t)r * NNZ_C;
    const float* rv = rel_vals + (size_t)r * NNZ_C;
#pragma unroll
    for (int i = 0; i < 16; ++i) {
        int e = blockIdx.x * 4096 + i * 256 + tid;
        if (e < NNZ_C) atomicAdd(&hist[rr[e] >> 9], 1);
    }
    __syncthreads();
    if (tid < NBK)
        gbase[tid] = bbase[r * (NBK + 1) + tid] +
                     (hist[tid] ? atomicAdd(&cursor[r * NBK + tid], hist[tid]) : 0);
    __syncthreads();
    int2* tp = tmp + (size_t)r * NNZ_C;
#pragma unroll
    for (int i = 0; i < 16; ++i) {
        int e = blockIdx.x * 4096 + i * 256 + tid;
        if (e < NNZ_C) {
            int row = rr[e];
            int bk = row >> 9;
            int rank = atomicAdd(&cur2[bk], 1);
            uint32 fb = __float_as_uint(rv[e]);
            uint32 pk = (uint32)rc[e] | (((fb >> 16) & 0x7FFFu) << 17);
            tp[gbase[bk] + rank] = make_int2((int)pk, row);
        }
    }
}

// B: refine one bucket: per-row offsets + row-sorted 4B records, all writes coalesced
__global__ __launch_bounds__(256) void bucket_refine_kernel(
    const int2* __restrict__ tmp, const int* __restrict__ bbase,
    int* __restrict__ offs, uint32* __restrict__ edges)
{
    __shared__ int cnt[512], offsL[512], cur[512];
    __shared__ uint32 outb[6656];
    const int b = blockIdx.x, r = blockIdx.y, tid = threadIdx.x;
    const int lane = tid & 63, wid = tid >> 6;
    const int row0 = b << 9;
    const int e0 = bbase[r * (NBK + 1) + b];
    const int e1 = bbase[r * (NBK + 1) + b + 1];
    cnt[tid] = 0; cnt[256 + tid] = 0; cur[tid] = 0; cur[256 + tid] = 0;
    __syncthreads();
    const int2* tp = tmp + (size_t)r * NNZ_C;
    for (int e = e0 + tid; e < e1; e += 256)
        atomicAdd(&cnt[tp[e].y - row0], 1);
    __syncthreads();
    if (wid == 0) {   // wave 0: exclusive scan of 512 counters
        int carry = 0;
        for (int c = 0; c < 8; ++c) {
            int x = cnt[c * 64 + lane];
            int inc = x;
#pragma unroll
            for (int d = 1; d < 64; d <<= 1) {
                int y = __shfl_up(inc, d, 64);
                if (lane >= d) inc += y;
            }
            offsL[c * 64 + lane] = inc - x + carry;
            carry += __shfl(inc, 63, 64);
        }
    }
    __syncthreads();
    // per-row global offsets (covers offs[70000] terminator via bucket 136)
    for (int i = tid; i < 512; i += 256) {
        int row = row0 + i;
        if (row < 70001) offs[(size_t)r * 70001 + row] = e0 + offsL[i];
    }
    for (int e = e0 + tid; e < e1; e += 256) {
        int2 E = tp[e];
        int lr_ = E.y - row0;
        int slot = offsL[lr_] + atomicAdd(&cur[lr_], 1);
        if (slot < 6656) outb[slot] = (uint32)E.x;
    }
    __syncthreads();
    uint32* eo = edges + (size_t)r * NNZ_C + e0;
    for (int i = tid; i < e1 - e0; i += 256) eo[i] = outb[i];
}

// ---------------- gather: t_r[row] = sum_e val * hab[col]  (wave/row, 4-deep MLP) --------
__global__ __launch_bounds__(256) void gather_kernel(
    const uint32* __restrict__ hab, const uint32* __restrict__ edges,
    const int* __restrict__ offs, uint32* __restrict__ T)
{
    const int r = blockIdx.y;
    const int row = blockIdx.x * 4 + (threadIdx.x >> 6);
    const int lane = threadIdx.x & 63;
    const uint32* __restrict__ ed = edges + (size_t)r * NNZ_C;
    const int* __restrict__ of = offs + (size_t)r * 70001;
    int e0 = of[row], e1 = of[row + 1];
    float ax = 0.f, ay = 0.f;
    int e = e0;
    for (; e + 4 <= e1; e += 4) {
        uint32 E0 = ed[e], E1 = ed[e + 1], E2 = ed[e + 2], E3 = ed[e + 3];
        uint32 u0 = hab[(size_t)(E0 & 0x1FFFFu) * 64 + lane];
        uint32 u1 = hab[(size_t)(E1 & 0x1FFFFu) * 64 + lane];
        uint32 u2 = hab[(size_t)(E2 & 0x1FFFFu) * 64 + lane];
        uint32 u3 = hab[(size_t)(E3 & 0x1FFFFu) * 64 + lane];
        float v0 = __uint_as_float((E0 >> 1) & 0x7FFF0000u);
        float v1 = __uint_as_float((E1 >> 1) & 0x7FFF0000u);
        float v2 = __uint_as_float((E2 >> 1) & 0x7FFF0000u);
        float v3 = __uint_as_float((E3 >> 1) & 0x7FFF0000u);
        ax += v0 * bflo(u0) + v1 * bflo(u1) + v2 * bflo(u2) + v3 * bflo(u3);
        ay += v0 * bfhi(u0) + v1 * bfhi(u1) + v2 * bfhi(u2) + v3 * bfhi(u3);
    }
    for (; e < e1; ++e) {
        uint32 E = ed[e];
        uint32 u = hab[(size_t)(E & 0x1FFFFu) * 64 + lane];
        float v = __uint_as_float((E >> 1) & 0x7FFF0000u);
        ax += v * bflo(u); ay += v * bfhi(u);
    }
    T[(size_t)row * 192 + r * 64 + lane] = packbf(ax, ay);
}

// ---------------- weight prep: Wcat[seg][n][r*128+k] = bf16( (U @ W_r)[n][k] ) ----------
__global__ __launch_bounds__(256, 3) void wprep_kernel(
    const float* __restrict__ upi_w, const float* __restrict__ upu_w,
    const float* __restrict__ lin_r_w, int k, uint32* __restrict__ Wcat)
{
    __shared__ float As[128][65];
    __shared__ __align__(8) bf16 Ws[128][66];
    const int which = blockIdx.y, seg = which / 3, r = which % 3;
    const float* U  = (seg == 0 ? upi_w : upu_w) + (size_t)k * 16384;
    const float* Wr = lin_r_w + (size_t)(k * 3 + r) * 16384;
    uint32* out = Wcat + (size_t)seg * 32768;   // u32 row stride 256 (512 bf16)
    const int tid = threadIdx.x;
    const int row0 = blockIdx.x * 64;
#pragma unroll
    for (int i = 0; i < 8; ++i) {
        int id = i * 256 + tid;
        int rr = id >> 5, c4 = (id & 31) << 2;
        float4 v = *(const float4*)&U[(size_t)(row0 + rr) * 128 + c4];
        As[c4][rr] = v.x; As[c4+1][rr] = v.y; As[c4+2][rr] = v.z; As[c4+3][rr] = v.w;
    }
    const int m0 = (tid & 15) * 4;
    const int n0 = (tid >> 4) * 8;
    float acc[4][8];
#pragma unroll
    for (int i = 0; i < 4; ++i)
#pragma unroll
        for (int j = 0; j < 8; ++j) acc[i][j] = 0.f;
    for (int p = 0; p < 2; ++p) {
        if (p) __syncthreads();
        for (int i = 0; i < 32; ++i) {       // Ws[c][kf] = Wr[p*64+kf][c] (transposed)
            int id = i * 256 + tid;
            int c = id >> 6, kf = id & 63;
            Ws[c][kf] = __float2bfloat16(Wr[(size_t)(p * 64 + kf) * 128 + c]);
        }
        __syncthreads();
        for (int k2 = 0; k2 < 32; ++k2) {
            int kk = p * 64 + 2 * k2;
            float av0[4], av1[4];
#pragma unroll
            for (int i = 0; i < 4; ++i) { av0[i] = As[kk][m0 + i]; av1[i] = As[kk + 1][m0 + i]; }
#pragma unroll
            for (int j = 0; j < 8; ++j) {
                uint32 wp = *(const uint32*)&Ws[n0 + j][2 * k2];
                float w0 = bflo(wp), w1 = bfhi(wp);
#pragma unroll
                for (int i = 0; i < 4; ++i)
                    acc[i][j] = fmaf(av1[i], w1, fmaf(av0[i], w0, acc[i][j]));
            }
        }
    }
#pragma unroll
    for (int i = 0; i < 4; ++i) {
        int n = row0 + m0 + i;
#pragma unroll
        for (int j = 0; j < 8; j += 2)
            out[(size_t)n * 256 + (r * 128 + n0 + j) / 2] = packbf(acc[i][j], acc[i][j + 1]);
    }
}

// ---------------- U pack: Wcat[seg][n][384+j] = bf16(U[n][j]) ----------------
__global__ __launch_bounds__(256) void upack_kernel(
    const float* __restrict__ upi_w, const float* __restrict__ upu_w,
    int k, uint32* __restrict__ Wcat)
{
    int id = blockIdx.x * 256 + threadIdx.x;   // 16384 pairs
    int seg = id >> 13, p = id & 8191;
    int n = p >> 6, j2 = (p & 63);
    const float* U = (seg ? upu_w : upi_w) + (size_t)k * 16384;
    float2 w = *(const float2*)&U[(size_t)n * 128 + j2 * 2];
    Wcat[(size_t)seg * 32768 + (size_t)n * 256 + 192 + j2] = packbf(w.x, w.y);
}

// ---------------- HGNN update (MFMA, LDS-free): hab = relu([T|hab] @ Wcat^T + b) ----------
__global__ __launch_bounds__(256) void hgnn_update_mfma_kernel(
    const bf16* __restrict__ T, uint32* __restrict__ hab,
    const bf16* __restrict__ Wcat, const float* __restrict__ bias, int row0, int M)
{
    const int tid = threadIdx.x;
    const int wv = tid >> 6, lane = tid & 63, quad = lane >> 4, lr = lane & 15;
    const int rbase = blockIdx.x * 64;
    const bf16* hb = (const bf16*)hab;
    f32x4 acc[4][2];
#pragma unroll
    for (int mt = 0; mt < 4; ++mt) { acc[mt][0] = (f32x4){0,0,0,0}; acc[mt][1] = (f32x4){0,0,0,0}; }
    int arow[4];
#pragma unroll
    for (int mt = 0; mt < 4; ++mt) {
        int rr = rbase + mt * 16 + lr;
        arow[mt] = row0 + (rr < M ? rr : M - 1);
    }
#pragma unroll
    for (int ks = 0; ks < 16; ++ks) {
        short8 b0 = *(const short8*)&Wcat[(size_t)(wv * 32 + lr) * 512 + ks * 32 + quad * 8];
        short8 b1 = *(const short8*)&Wcat[(size_t)(wv * 32 + 16 + lr) * 512 + ks * 32 + quad * 8];
#pragma unroll
        for (int mt = 0; mt < 4; ++mt) {
            short8 a;
            if (ks < 12) a = *(const short8*)&T[(size_t)arow[mt] * 384 + ks * 32 + quad * 8];
            else         a = *(const short8*)&hb[(size_t)arow[mt] * 128 + (ks - 12) * 32 + quad * 8];
            acc[mt][0] = __builtin_amdgcn_mfma_f32_16x16x32_bf16(a, b0, acc[mt][0], 0, 0, 0);
            acc[mt][1] = __builtin_amdgcn_mfma_f32_16x16x32_bf16(a, b1, acc[mt][1], 0, 0, 0);
        }
    }
    __syncthreads();   // drain loads: all hab reads done before in-place writes
    unsigned short* hw = (unsigned short*)hab;
#pragma unroll
    for (int s = 0; s < 2; ++s) {
        int col = wv * 32 + s * 16 + lr;
        float bv = bias[col];
#pragma unroll
        for (int mt = 0; mt < 4; ++mt)
#pragma unroll
            for (int reg = 0; reg < 4; ++reg) {
                int rr = rbase + mt * 16 + quad * 4 + reg;
                if (rr < M) {
                    float v = fmaxf(acc[mt][s][reg] + bv, 0.f);
                    hw[(size_t)(row0 + rr) * 128 + col] = __bfloat16_as_ushort(__float2bfloat16(v));
                }
            }
    }
}

// ---------------- generic MFMA NT gemm (LDS-free, bf16 A/W, 1-2 outputs) ----------------
__global__ __launch_bounds__(256) void mfma_nt_kernel(
    const bf16* __restrict__ A, const int* __restrict__ rowmap,
    const bf16* __restrict__ W0, const bf16* __restrict__ W1,
    const float* __restrict__ b0, const float* __restrict__ b1,
    float* __restrict__ O0, float* __restrict__ O1, int M)
{
    const int tid = threadIdx.x;
    const int wv = tid >> 6, lane = tid & 63, quad = lane >> 4, lr = lane & 15;
    const int rbase = blockIdx.x * 64;
    int arow[4];
#pragma unroll
    for (int mt = 0; mt < 4; ++mt) {
        int rr = rbase + mt * 16 + lr;
        rr = rr < M ? rr : M - 1;
        arow[mt] = rowmap ? rowmap[rr] : rr;
    }
    f32x4 acc0[4][2], acc1[4][2];
#pragma unroll
    for (int mt = 0; mt < 4; ++mt) {
        acc0[mt][0] = (f32x4){0,0,0,0}; acc0[mt][1] = (f32x4){0,0,0,0};
        acc1[mt][0] = (f32x4){0,0,0,0}; acc1[mt][1] = (f32x4){0,0,0,0};
    }
#pragma unroll
    for (int ks = 0; ks < 4; ++ks) {
        short8 b00 = *(const short8*)&W0[(size_t)(wv * 32 + lr) * 128 + ks * 32 + quad * 8];
        short8 b01 = *(const short8*)&W0[(size_t)(wv * 32 + 16 + lr) * 128 + ks * 32 + quad * 8];
        short8 b10, b11;
        if (W1) {
            b10 = *(const short8*)&W1[(size_t)(wv * 32 + lr) * 128 + ks * 32 + quad * 8];
            b11 = *(const short8*)&W1[(size_t)(wv * 32 + 16 + lr) * 128 + ks * 32 + quad * 8];
        }
#pragma unroll
        for (int mt = 0; mt < 4; ++mt) {
            short8 a = *(const short8*)&A[(size_t)arow[mt] * 128 + ks * 32 + quad * 8];
            acc0[mt][0] = __builtin_amdgcn_mfma_f32_16x16x32_bf16(a, b00, acc0[mt][0], 0, 0, 0);
            acc0[mt][1] = __builtin_amdgcn_mfma_f32_16x16x32_bf16(a, b01, acc0[mt][1], 0, 0, 0);
            if (W1) {
                acc1[mt][0] = __builtin_amdgcn_mfma_f32_16x16x32_bf16(a, b10, acc1[mt][0], 0, 0, 0);
                acc1[mt][1] = __builtin_amdgcn_mfma_f32_16x16x32_bf16(a, b11, acc1[mt][1], 0, 0, 0);
            }
        }
    }
#pragma unroll
    for (int s = 0; s < 2; ++s) {
        int col = wv * 32 + s * 16 + lr;
        float bv0 = b0 ? b0[col] : 0.f;
        float bv1 = (W1 && b1) ? b1[col] : 0.f;
#pragma unroll
        for (int mt = 0; mt < 4; ++mt)
#pragma unroll
            for (int reg = 0; reg < 4; ++reg) {
                int rr = rbase + mt * 16 + quad * 4 + reg;
                if (rr < M) {
                    O0[(size_t)rr * 128 + col] = acc0[mt][s][reg] + bv0;
                    if (W1) O1[(size_t)rr * 128 + col] = acc1[mt][s][reg] + bv1;
                }
            }
    }
}

// ---------------- session prep ----------------
__global__ void session_prep_kernel(const int* __restrict__ ids, const int* __restrict__ uid,
                                    const float* __restrict__ u_type,
                                    int* __restrict__ lens, int* __restrict__ rowmap,
                                    float* __restrict__ out_target, float* __restrict__ out_utype)
{
    int n = blockIdx.x * 256 + threadIdx.x;
    if (n >= NSESS) return;
    int b = n & 255, s = n >> 8;
    const int* row = ids + (size_t)(b * 4 + s) * 50;
    int len = 0;
#pragma unroll
    for (int l = 0; l < 50; ++l) len += (row[l] != 0) ? 1 : 0;
    lens[n] = len;
    rowmap[n] = n * LP + (len - 2);
    out_target[n] = (float)row[len - 1];
    out_utype[n] = u_type[b];
}

// ---------------- c_hist gather from bf16 hab ----------------
__global__ void chist_kernel(const uint32* __restrict__ hab, const int* __restrict__ uid,
                             float* __restrict__ chist) {
    int n = blockIdx.x, d = threadIdx.x;
    uint32 u = hab[(size_t)(N_ITEMS_C + uid[n & 255]) * 64 + (d >> 1)];
    chist[(size_t)n * 128 + d] = (d & 1) ? bfhi(u) : bflo(u);
}

// ---------------- token embedding gather -> bf16 h ----------------
__global__ void h0_gather_kernel(const float* __restrict__ id_emb, const int* __restrict__ ids,
                                 const int* __restrict__ lens, uint32* __restrict__ hb) {
    int g = blockIdx.x, d = threadIdx.x;   // 64 threads, d = pair index
    int n = g / LP;
    int tt = g - n * LP;
    int len = lens[n];
    int b = n & 255, s = n >> 8;
    int id = (tt < len - 1) ? ids[(size_t)(b * 4 + s) * 50 + tt] : 0;
    float2 e = *(const float2*)&id_emb[(size_t)id * 128 + d * 2];
    hb[(size_t)g * 64 + d] = packbf(e.x, e.y);
}

// ---------------- pack all session weights f32 -> bf16 ----------------
__global__ __launch_bounds__(256) void epack_kernel(
    const float* __restrict__ w_ih, const float* __restrict__ w_hh,
    const float* __restrict__ ei_w, const float* __restrict__ eo_w,
    const float* __restrict__ q2_w, const float* __restrict__ q1_w,
    uint32* __restrict__ dst)
{
    int id = blockIdx.x * 256 + threadIdx.x;   // 106,496 pairs total
    const float* src; int off;
    if      (id <  49152) { src = w_ih; off = id; }
    else if (id <  73728) { src = w_hh; off = id - 49152; }
    else if (id <  81920) { src = ei_w; off = id - 73728; }
    else if (id <  90112) { src = eo_w; off = id - 81920; }
    else if (id <  98304) { src = q2_w; off = id - 90112; }
    else                  { src = q1_w; off = id - 98304; }
    float2 w = *(const float2*)&src[(size_t)off * 2];
    dst[id] = packbf(w.x, w.y);
}

// ---------------- MFMA GRU over bf16 h (in-place) ----------------
__global__ __launch_bounds__(256, 2) void gru_mfma_kernel(
    const float* __restrict__ hEi, const float* __restrict__ hEo,
    uint32* __restrict__ hb, const int* __restrict__ lens,
    const bf16* __restrict__ wihb,   // [384][256] bf16
    const bf16* __restrict__ whhb,   // [384][128] bf16
    const float* __restrict__ b_ih, const float* __restrict__ b_hh,
    const float* __restrict__ b_iah, const float* __restrict__ b_oah)
{
    __shared__ __align__(16) bf16 Agi[16][264];
    __shared__ __align__(16) bf16 Agh[16][136];
    const int tid = threadIdx.x;
    const int g0 = blockIdx.x * 16;

#pragma unroll
    for (int i = 0; i < 8; ++i) {
        int p = i * 256 + tid;
        int row = p >> 7, kp = p & 127;
        int g = g0 + row;
        int n = g / LP;
        int tt = g - n * LP;
        int len = lens[n];
        int kk = (kp & 63) * 2;
        float v0, v1;
        if (kp < 64) {
            v0 = b_iah[kk]; v1 = b_iah[kk + 1];
            if (tt >= 1 && tt < len - 1) {
                float2 e = *(const float2*)&hEi[(size_t)(g - 1) * 128 + kk];
                v0 += e.x; v1 += e.y;
            }
        } else {
            v0 = b_oah[kk]; v1 = b_oah[kk + 1];
            if (tt < len - 2) {
                float2 e = *(const float2*)&hEo[(size_t)(g + 1) * 128 + kk];
                v0 += e.x; v1 += e.y;
            }
        }
        *(uint32*)&Agi[row][kp * 2] = packbf(v0, v1);
    }
#pragma unroll
    for (int i = 0; i < 4; ++i) {
        int p = i * 256 + tid;
        int row = p >> 6, kp = p & 63;
        *(uint32*)&Agh[row][kp * 2] = hb[(size_t)(g0 + row) * 64 + kp];
    }
    __syncthreads();

    const int wv = tid >> 6;
    const int lane = tid & 63;
    const int quad = lane >> 4;
    const int lr = lane & 15;
    const int c0 = wv * 32;

    f32x4 accI[2][3], accH[2][3];
#pragma unroll
    for (int s = 0; s < 2; ++s)
#pragma unroll
        for (int gte = 0; gte < 3; ++gte) {
            accI[s][gte] = (f32x4){0.f, 0.f, 0.f, 0.f};
            accH[s][gte] = (f32x4){0.f, 0.f, 0.f, 0.f};
        }

#pragma unroll
    for (int ks = 0; ks < 8; ++ks) {
        short8 a = *(const short8*)&Agi[lr][ks * 32 + quad * 8];
#pragma unroll
        for (int s = 0; s < 2; ++s)
#pragma unroll
            for (int gte = 0; gte < 3; ++gte) {
                int n0 = gte * 128 + c0 + s * 16 + lr;
                short8 b = *(const short8*)&wihb[(size_t)n0 * 256 + ks * 32 + quad * 8];
                accI[s][gte] = __builtin_amdgcn_mfma_f32_16x16x32_bf16(a, b, accI[s][gte], 0, 0, 0);
            }
    }
#pragma unroll
    for (int ks = 0; ks < 4; ++ks) {
        short8 a = *(const short8*)&Agh[lr][ks * 32 + quad * 8];
#pragma unroll
        for (int s = 0; s < 2; ++s)
#pragma unroll
            for (int gte = 0; gte < 3; ++gte) {
                int n0 = gte * 128 + c0 + s * 16 + lr;
                short8 b = *(const short8*)&whhb[(size_t)n0 * 128 + ks * 32 + quad * 8];
                accH[s][gte] = __builtin_amdgcn_mfma_f32_16x16x32_bf16(a, b, accH[s][gte], 0, 0, 0);
            }
    }

    unsigned short* hu = (unsigned short*)hb;
#pragma unroll
    for (int s = 0; s < 2; ++s) {
        int col = c0 + s * 16 + lr;
        float bir = b_ih[col], biz = b_ih[col + 128], bin = b_ih[col + 256];
        float bhr = b_hh[col], bhz = b_hh[col + 128], bhn = b_hh[col + 256];
#pragma unroll
        for (int reg = 0; reg < 4; ++reg) {
            int row = g0 + quad * 4 + reg;
            float gi_r = accI[s][0][reg] + bir, gh_r = accH[s][0][reg] + bhr;
            float gi_z = accI[s][1][reg] + biz, gh_z = accH[s][1][reg] + bhz;
            float gi_n = accI[s][2][reg] + bin, gh_n = accH[s][2][reg] + bhn;
            float rg = 1.f / (1.f + expf(-(gi_r + gh_r)));
            float zg = 1.f / (1.f + expf(-(gi_z + gh_z)));
            float ng = tanhf(gi_n + rg * gh_n);
            size_t idx = (size_t)row * 128 + col;
            float ho = __uint_as_float((uint32)hu[idx] << 16);
            hu[idx] = __bfloat16_as_ushort(__float2bfloat16(ng + zg * (ho - ng)));
        }
    }
}

// ---------------- attention readout + fuse layer -> reps (f32 out) ----------------
__global__ __launch_bounds__(128) void attn_fuse_kernel(
    const float* __restrict__ q1h, const float* __restrict__ q2h,
    const unsigned short* __restrict__ hu, const float* __restrict__ chist,
    const int* __restrict__ lens, const float* __restrict__ att_w,
    const float* __restrict__ fuse_w, const float* __restrict__ fuse_b,
    float* __restrict__ out)
{
    __shared__ float q1s[128], aws[128], al[64], cv[256];
    const int n = blockIdx.x, tid = threadIdx.x;
    q1s[tid] = q1h[(size_t)n * 128 + tid];
    aws[tid] = att_w[tid];
    if (tid < 64) al[tid] = 0.f;
    __syncthreads();
    const int len = lens[n];
    if (tid < len - 1) {
        const float* q2 = &q2h[(size_t)(n * LP + tid) * 128];
        float s = 0.f;
        for (int d = 0; d < 128; ++d) {
            float x = q1s[d] + q2[d];
            s += aws[d] / (1.f + expf(-x));
        }
        al[tid] = s;
    }
    __syncthreads();
    float ssum = 0.f;
    for (int t = 0; t < len - 1; ++t) ssum += al[t];
    float inv = 1.f / (ssum + 1e-8f);
    float c = 0.f;
    for (int t = 0; t < len - 1; ++t) {
        float hv = __uint_as_float((uint32)hu[(size_t)(n * LP + t) * 128 + tid] << 16);
        c += al[t] * inv * hv;
    }
    cv[tid] = c;
    cv[128 + tid] = chist[(size_t)n * 128 + tid];
    __syncthreads();
    float s = fuse_b[tid];
    const float* fr = fuse_w + (size_t)tid * 256;
    for (int k = 0; k < 256; ++k) s += cv[k] * fr[k];
    out[(size_t)n * 128 + tid] = s;
}

// ============================================================================
extern "C" void kernel_launch(void* const* d_in, const int* in_sizes, int n_in,
                              void* d_out, int out_size, void* d_ws, size_t ws_size,
                              hipStream_t stream)
{
    const float* id_emb   = (const float*)d_in[0];
    const float* user_emb = (const float*)d_in[1];
    const float* lin_r_w  = (const float*)d_in[2];
    const float* upi_w    = (const float*)d_in[3];
    const float* upi_b    = (const float*)d_in[4];
    const float* upu_w    = (const float*)d_in[5];
    const float* upu_b    = (const float*)d_in[6];
    const float* w_ih     = (const float*)d_in[7];
    const float* w_hh     = (const float*)d_in[8];
    const float* b_ih     = (const float*)d_in[9];
    const float* b_hh     = (const float*)d_in[10];
    const float* b_iah    = (const float*)d_in[11];
    const float* b_oah    = (const float*)d_in[12];
    const float* ei_w     = (const float*)d_in[13];
    const float* ei_b     = (const float*)d_in[14];
    const float* eo_w     = (const float*)d_in[15];
    const float* eo_b     = (const float*)d_in[16];
    const float* q1_w     = (const float*)d_in[17];
    const float* q2_w     = (const float*)d_in[18];
    const float* att_w    = (const float*)d_in[19];
    const float* fuse_w   = (const float*)d_in[20];
    const float* fuse_b   = (const float*)d_in[21];
    const int*  rel_rows  = (const int*)d_in[22];
    const int*  rel_cols  = (const int*)d_in[23];
    const float* rel_vals = (const float*)d_in[24];
    const int*  ids       = (const int*)d_in[25];
    const int*  uid       = (const int*)d_in[26];
    const float* u_type   = (const float*)d_in[27];
    float* out = (float*)d_out;   // reps[131072] | target[1024] | u_type[1024]

    // ---- workspace layout (u32 units) ----
    uint32* W32    = (uint32*)d_ws;
    uint32* hab    = W32;                                 //  4,480,000 (bf16 nodes)
    uint32* T      = W32 + 4480000;                       // 13,440,000 (bf16, stride 192)
    uint32* edges  = W32 + 17920000;                      //  2,400,000 (4B records)
    int2*   tmp    = (int2*)(W32 + 20320000);             //  2,400,000 int2
    int*    offs   = (int*)(W32 + 25120000);              //  3 x 70001 (pad 210,004)
    int*    bhist  = (int*)(W32 + 25330004);              //  3 x 137
    int*    cursor = (int*)(W32 + 25330415);              //  3 x 137
    int*    bbase  = (int*)(W32 + 25330826);              //  3 x 138
    uint32* Wcat   = W32 + 25331240;                      //  2 x 32768
    float*  q1h    = (float*)(W32 + 25396776);            //  131,072
    float*  chist  = (float*)(W32 + 25527848);            //  131,072
    int*    lens   = (int*)(W32 + 25658920);              //  1024
    int*    rowmap = (int*)(W32 + 25659944);              //  1024  (end 25,660,968)
    // session overlays (live only after HGNN):
    uint32* sess_hb = W32;                                // 3,211,264 u32 (bf16 h, over hab)
    float* sess_Ei  = (float*)(W32 + 4480000);            // 6,422,528 f (in T region)
    float* sess_Eo  = (float*)(W32 + 10902528);           // 6,422,528 f (in T region)
    float* q2h      = sess_Ei;                            // Ei dead after GRU
    uint32* wpk     = W32 + 17920000;                     // packed session wts (over edges)
    uint32* wihb = wpk;              // 49,152
    uint32* whhb = wpk + 49152;      // 24,576
    uint32* eiwb = wpk + 73728;      //  8,192
    uint32* eowb = wpk + 81920;      //  8,192
    uint32* q2wb = wpk + 90112;      //  8,192
    uint32* q1wb = wpk + 98304;      //  8,192
    if (ws_size < (size_t)27144192 * 4 + 4096) return;

    // ---- init + bucket-sort CSR build (coalesced writes, no 70001-scan) ----
    init_hab_kernel<<<17500, 256, 0, stream>>>((const float2*)id_emb, (const float2*)user_emb, hab);
    hipMemsetAsync(bhist, 0, (size_t)822 * 4, stream);    // bhist + cursor
    bucket_hist_kernel<<<dim3(196, 3), 256, 0, stream>>>(rel_rows, bhist);
    bucket_scan_kernel<<<1, 256, 0, stream>>>(bhist, bbase);
    bucket_scatter_kernel<<<dim3(196, 3), 256, 0, stream>>>(rel_rows, rel_cols, rel_vals,
                                                            bbase, cursor, tmp);
    bucket_refine_kernel<<<dim3(NBK, 3), 256, 0, stream>>>(tmp, bbase, offs, edges);

    // ---- HGNN: 2 layers, MFMA update, no atomics ----
    for (int k = 0; k < 2; ++k) {
        wprep_kernel<<<dim3(2, 6), 256, 0, stream>>>(upi_w, upu_w, lin_r_w, k, Wcat);
        upack_kernel<<<64, 256, 0, stream>>>(upi_w, upu_w, k, Wcat);
        gather_kernel<<<dim3(17500, 3), 256, 0, stream>>>(hab, edges, offs, T);
        hgnn_update_mfma_kernel<<<782, 256, 0, stream>>>((const bf16*)T, hab,
            (const bf16*)Wcat, upi_b + k * 128, 0, N_ITEMS_C);
        hgnn_update_mfma_kernel<<<313, 256, 0, stream>>>((const bf16*)T, hab,
            (const bf16*)(Wcat + 32768), upu_b + k * 128, N_ITEMS_C, N_USERS_C);
    }

    // ---- session branch ----
    session_prep_kernel<<<4, 256, 0, stream>>>(ids, uid, u_type, lens, rowmap,
        out + 131072, out + 132096);
    chist_kernel<<<NSESS, 128, 0, stream>>>(hab, uid, chist);   // before sess_hb overwrites hab
    epack_kernel<<<416, 256, 0, stream>>>(w_ih, w_hh, ei_w, eo_w, q2_w, q1_w, wpk);
    h0_gather_kernel<<<NTOK, 64, 0, stream>>>(id_emb, ids, lens, sess_hb);
    mfma_nt_kernel<<<784, 256, 0, stream>>>((const bf16*)sess_hb, nullptr,
        (const bf16*)eiwb, (const bf16*)eowb, ei_b, eo_b, sess_Ei, sess_Eo, NTOK);
    gru_mfma_kernel<<<NTOK / 16, 256, 0, stream>>>(sess_Ei, sess_Eo, sess_hb, lens,
        (const bf16*)wihb, (const bf16*)whhb, b_ih, b_hh, b_iah, b_oah);
    mfma_nt_kernel<<<784, 256, 0, stream>>>((const bf16*)sess_hb, nullptr,
        (const bf16*)q2wb, nullptr, nullptr, nullptr, q2h, nullptr, NTOK);
    mfma_nt_kernel<<<16, 256, 0, stream>>>((const bf16*)sess_hb, rowmap,
        (const bf16*)q1wb, nullptr, nullptr, nullptr, q1h, nullptr, NSESS);
    attn_fuse_kernel<<<NSESS, 128, 0, stream>>>(q1h, q2h, (const unsigned short*)sess_hb,
        chist, lens, att_w, fuse_w, fuse_b, out);
}